// Round 1
// baseline (499.086 us; speedup 1.0000x reference)
//
#include <hip/hip_runtime.h>

// ---------------------------------------------------------------------------
// PyramidNSMLayer: 4-level anchor decode + top-4000 selection + greedy NMS.
//
// Pipeline (all on `stream`, graph-capturable, deterministic):
//   1. memset hist/counter (ws)
//   2. hist_kernel:    8192-bin histogram of all 3,133,440 scores
//   3. select_kernel:  smallest bin B with suffix-count >= 4000
//   4. compact_kernel: gather (score,index) keys for bin >= B  (~4.4K items)
//   5. sortdecode:     bitonic sort 8192 keys desc (score,-index), decode top 4000 boxes
//   6. iou_kernel:     4000 x 4096 bitmask of IoU > 0.5
//   7. greedy_kernel:  1-wave serial greedy scan, emit up to 300 rois
// ---------------------------------------------------------------------------

namespace {

constexpr int kNTot = 3133440;   // total anchors across levels
constexpr int kB1 = 2359296;     // 512*512*9
constexpr int kB2 = 2949120;     // + 256*256*9
constexpr int kB3 = 3096576;     // + 128*128*9
constexpr int kNBins = 8192;
constexpr int kCap = 8192;       // candidate buffer capacity (pow2 for bitonic)
constexpr int kTopK = 4000;
constexpr int kNPad = 4096;      // padded candidate count for 64-bit words
constexpr int kNRois = 300;

// ws byte offsets
constexpr size_t kOffHist    = 0;        // 8192 * u32  = 32768
constexpr size_t kOffCounter = 32768;    // u32
constexpr size_t kOffSel     = 32772;    // u32
constexpr size_t kOffKeys    = 65536;    // 8192 * u64  = 65536
constexpr size_t kOffBoxes   = 131072;   // 4096 * float4 = 65536
constexpr size_t kOffScores  = 196608;   // 4096 * float  = 16384
constexpr size_t kOffRows    = 212992;   // 4000 * 64 * u64 = 2048000
// total ws usage: 2,260,992 bytes

__device__ __forceinline__ float load_score(int g,
                                            const float* __restrict__ x1,
                                            const float* __restrict__ x2,
                                            const float* __restrict__ x3,
                                            const float* __restrict__ x4) {
  const float* x;
  int local;
  if (g < kB1)      { x = x1; local = g; }
  else if (g < kB2) { x = x2; local = g - kB1; }
  else if (g < kB3) { x = x3; local = g - kB2; }
  else              { x = x4; local = g - kB3; }
  int cell = local / 9;
  int kk = local - cell * 9;
  // layout (h, w, 9, 6): channel 6k+0 is the fg score
  return x[(size_t)cell * 54 + kk * 6];
}

__device__ __forceinline__ int score_bin(float s) {
  int b = (int)(s * (float)kNBins);
  return min(max(b, 0), kNBins - 1);
}

__global__ void hist_kernel(const float* __restrict__ x1, const float* __restrict__ x2,
                            const float* __restrict__ x3, const float* __restrict__ x4,
                            unsigned* __restrict__ hist) {
  int g = blockIdx.x * blockDim.x + threadIdx.x;
  if (g >= kNTot) return;
  float s = load_score(g, x1, x2, x3, x4);
  atomicAdd(&hist[score_bin(s)], 1u);
}

// 1 block, 256 threads: find smallest bin B with suffix-count >= kTopK.
__global__ void select_kernel(const unsigned* __restrict__ hist, unsigned* __restrict__ sel) {
  __shared__ unsigned csum[256];
  unsigned t = 0;
  int c0 = threadIdx.x * 32;
  for (int b = c0; b < c0 + 32; ++b) t += hist[b];
  csum[threadIdx.x] = t;
  __syncthreads();
  if (threadIdx.x == 0) {
    unsigned acc = 0;
    int B = 0;
    int c;
    for (c = 255; c >= 0; --c) {
      if (acc + csum[c] >= (unsigned)kTopK) break;
      acc += csum[c];
    }
    if (c >= 0) {
      int b;
      for (b = c * 32 + 31; b >= c * 32; --b) {
        acc += hist[b];
        if (acc >= (unsigned)kTopK) break;
      }
      B = max(b, 0);
    }
    sel[0] = (unsigned)B;
  }
}

__global__ void compact_kernel(const float* __restrict__ x1, const float* __restrict__ x2,
                               const float* __restrict__ x3, const float* __restrict__ x4,
                               const unsigned* __restrict__ sel,
                               unsigned* __restrict__ counter,
                               unsigned long long* __restrict__ keys) {
  int g = blockIdx.x * blockDim.x + threadIdx.x;
  if (g >= kNTot) return;
  float s = load_score(g, x1, x2, x3, x4);
  if ((unsigned)score_bin(s) >= sel[0]) {
    unsigned pos = atomicAdd(counter, 1u);
    if (pos < (unsigned)kCap) {
      // key: high 32 = score bits (scores >= 0 so monotonic), low 32 = ~index
      // -> sorting keys DESC gives (score desc, index asc) == lax.top_k order.
      keys[pos] = ((unsigned long long)__float_as_uint(s) << 32) |
                  (unsigned long long)(0xFFFFFFFFu - (unsigned)g);
    }
  }
}

__device__ __forceinline__ void decode_box(unsigned g,
                                           const float* __restrict__ x1, const float* __restrict__ x2,
                                           const float* __restrict__ x3, const float* __restrict__ x4,
                                           const float* __restrict__ a1, const float* __restrict__ a2,
                                           const float* __restrict__ a3, const float* __restrict__ a4,
                                           float4* box) {
  const float* x;
  const float* anc;
  unsigned local;
  if (g < (unsigned)kB1)      { x = x1; anc = a1; local = g; }
  else if (g < (unsigned)kB2) { x = x2; anc = a2; local = g - kB1; }
  else if (g < (unsigned)kB3) { x = x3; anc = a3; local = g - kB2; }
  else                        { x = x4; anc = a4; local = g - kB3; }
  unsigned cell = local / 9u;
  unsigned kk = local - cell * 9u;
  const float* xe = x + (size_t)cell * 54 + kk * 6;
  float dy = xe[2], dx = xe[3], dh = xe[4], dwv = xe[5];
  const float* ae = anc + (size_t)local * 4;
  float ay1 = ae[0], ax1 = ae[1], ay2 = ae[2], ax2 = ae[3];
  float ah = ay2 - ay1;
  float aw = ax2 - ax1;
  float acy = ay1 + 0.5f * ah;
  float acx = ax1 + 0.5f * aw;
  float cy = acy + dy * ah;
  float cx = acx + dx * aw;
  float bh = ah * expf(dh);
  float bw = aw * expf(dwv);
  box->x = fminf(fmaxf(cy - 0.5f * bh, 0.0f), 2048.0f);
  box->y = fminf(fmaxf(cx - 0.5f * bw, 0.0f), 2048.0f);
  box->z = fminf(fmaxf(cy + 0.5f * bh, 0.0f), 2048.0f);
  box->w = fminf(fmaxf(cx + 0.5f * bw, 0.0f), 2048.0f);
}

// 1 block, 1024 threads, 64KB dynamic LDS. Bitonic sort 8192 keys desc,
// then decode first 4000 into boxes/scores (padded to 4096 with zeros).
__global__ void sortdecode_kernel(const unsigned long long* __restrict__ keys,
                                  const unsigned* __restrict__ counter,
                                  const float* __restrict__ x1, const float* __restrict__ x2,
                                  const float* __restrict__ x3, const float* __restrict__ x4,
                                  const float* __restrict__ a1, const float* __restrict__ a2,
                                  const float* __restrict__ a3, const float* __restrict__ a4,
                                  float4* __restrict__ boxes, float* __restrict__ scores) {
  extern __shared__ unsigned long long skeys[];
  unsigned n = min(*counter, (unsigned)kCap);
  int tid = threadIdx.x;
  for (int i = tid; i < kCap; i += 1024) skeys[i] = (i < (int)n) ? keys[i] : 0ull;
  __syncthreads();
  for (unsigned k = 2; k <= (unsigned)kCap; k <<= 1) {
    for (unsigned j = k >> 1; j > 0; j >>= 1) {
      for (unsigned i = tid; i < (unsigned)kCap; i += 1024) {
        unsigned ixj = i ^ j;
        if (ixj > i) {
          unsigned long long va = skeys[i], vb = skeys[ixj];
          bool up = ((i & k) == 0);  // descending network
          if (up ? (va < vb) : (va > vb)) { skeys[i] = vb; skeys[ixj] = va; }
        }
      }
      __syncthreads();
    }
  }
  for (int i = tid; i < kNPad; i += 1024) {
    unsigned long long key = (i < kTopK) ? skeys[i] : 0ull;
    float4 box = make_float4(0.f, 0.f, 0.f, 0.f);
    float sc = 0.f;
    if (key != 0ull) {
      unsigned sb = (unsigned)(key >> 32);
      unsigned g = 0xFFFFFFFFu - (unsigned)(key & 0xFFFFFFFFull);
      sc = __uint_as_float(sb);
      if (g < (unsigned)kNTot) {
        decode_box(g, x1, x2, x3, x4, a1, a2, a3, a4, &box);
      }
    }
    boxes[i] = box;
    scores[i] = sc;
  }
}

// One wave per 64-column word: rows[i][w] bit j = (IoU(box_i, box_{64w+j}) > 0.5)
__global__ void iou_kernel(const float4* __restrict__ boxes,
                           unsigned long long* __restrict__ rows) {
  int wave = (blockIdx.x * blockDim.x + threadIdx.x) >> 6;
  int lane = threadIdx.x & 63;
  if (wave >= kTopK * 64) return;
  int row = wave >> 6;
  int wc = wave & 63;
  int j = wc * 64 + lane;
  float4 bi = boxes[row];
  float4 bj = boxes[j];
  float yy1 = fmaxf(bi.x, bj.x);
  float xx1 = fmaxf(bi.y, bj.y);
  float yy2 = fminf(bi.z, bj.z);
  float xx2 = fminf(bi.w, bj.w);
  float inter = fmaxf(yy2 - yy1, 0.0f) * fmaxf(xx2 - xx1, 0.0f);
  float ar1 = (bi.z - bi.x) * (bi.w - bi.y);
  float ar2 = (bj.z - bj.x) * (bj.w - bj.y);
  float iou = inter / (ar1 + ar2 - inter + 1e-9f);
  unsigned long long m = __ballot(iou > 0.5f);
  if (lane == 0) rows[(size_t)row * 64 + wc] = m;
}

// 1 wave. suppressed mask lives in registers: lane l holds word l (64 indices).
__global__ void greedy_kernel(const float4* __restrict__ boxes,
                              const float* __restrict__ scores,
                              const unsigned long long* __restrict__ rows,
                              float* __restrict__ out) {
  int lane = threadIdx.x;
  unsigned long long sup = 0ull;
  // pre-suppress everything below SCORE_THR (incl. zero padding): such entries
  // can never be emitted nor suppress anything (matches reference s=-1 rows).
  for (int c = 0; c < 64; ++c) {
    float s = scores[c * 64 + lane];
    unsigned long long inval = __ballot(!(s >= 0.5f));
    if (lane == c) sup = inval;
  }
  int count = 0;
  while (count < kNRois) {
    unsigned long long t = ~sup;
    int cand = t ? ((lane << 6) + __builtin_ctzll(t)) : 0x7fffffff;
    #pragma unroll
    for (int off = 32; off > 0; off >>= 1) cand = min(cand, __shfl_xor(cand, off));
    if (cand >= kNPad) break;  // nothing alive
    int j = cand;
    if (lane < 4) out[count * 4 + lane] = ((const float*)boxes)[j * 4 + lane];
    // explicit self-suppression (matches s.at[i].set(-1); needed for
    // degenerate zero-area boxes whose self-IoU is 0).
    if (lane == (j >> 6)) sup |= 1ull << (j & 63);
    sup |= rows[(size_t)j * 64 + lane];
    ++count;
  }
}

}  // namespace

extern "C" void kernel_launch(void* const* d_in, const int* in_sizes, int n_in,
                              void* d_out, int out_size, void* d_ws, size_t ws_size,
                              hipStream_t stream) {
  const float* x1 = (const float*)d_in[0];
  const float* a1 = (const float*)d_in[1];
  const float* x2 = (const float*)d_in[2];
  const float* a2 = (const float*)d_in[3];
  const float* x3 = (const float*)d_in[4];
  const float* a3 = (const float*)d_in[5];
  const float* x4 = (const float*)d_in[6];
  const float* a4 = (const float*)d_in[7];

  char* ws = (char*)d_ws;
  unsigned* hist = (unsigned*)(ws + kOffHist);
  unsigned* counter = (unsigned*)(ws + kOffCounter);
  unsigned* sel = (unsigned*)(ws + kOffSel);
  unsigned long long* keys = (unsigned long long*)(ws + kOffKeys);
  float4* boxes = (float4*)(ws + kOffBoxes);
  float* scores = (float*)(ws + kOffScores);
  unsigned long long* rows = (unsigned long long*)(ws + kOffRows);
  float* out = (float*)d_out;

  // per-call re-init (harness does not re-poison between replays)
  hipMemsetAsync(ws, 0, kOffSel + 4, stream);
  hipMemsetAsync(d_out, 0, (size_t)kNRois * 4 * sizeof(float), stream);

  int blocks = (kNTot + 255) / 256;
  hist_kernel<<<blocks, 256, 0, stream>>>(x1, x2, x3, x4, hist);
  select_kernel<<<1, 256, 0, stream>>>(hist, sel);
  compact_kernel<<<blocks, 256, 0, stream>>>(x1, x2, x3, x4, sel, counter, keys);
  sortdecode_kernel<<<1, 1024, kCap * sizeof(unsigned long long), stream>>>(
      keys, counter, x1, x2, x3, x4, a1, a2, a3, a4, boxes, scores);
  iou_kernel<<<(kTopK * 64 * 64) / 256, 256, 0, stream>>>(boxes, rows);
  greedy_kernel<<<1, 64, 0, stream>>>(boxes, scores, rows, out);
}

// Round 2
// 388.603 us; speedup vs baseline: 1.2843x; 1.2843x over previous
//
#include <hip/hip_runtime.h>

// ---------------------------------------------------------------------------
// PyramidNSMLayer: 4-level anchor decode + top-4000 selection + greedy NMS.
//
// Pipeline (all on `stream`, graph-capturable, deterministic):
//   1. memset hist/counter (ws)
//   2. hist_kernel:    8192-bin histogram of all 3,133,440 scores (4/thread, float4)
//   3. select_kernel:  smallest bin B with suffix-count >= 4000
//   4. compact_kernel: gather (score,index) keys for bin >= B  (~4.4K items)
//   5. sortdecode:     bitonic sort 8192 keys desc (score,-index), decode top
//                      4000 boxes, emit sup-init bitmask (score<0.5 -> dead)
//   6. iou_kernel:     4000 x 4096 bitmask of IoU > 0.5
//   7. greedy_kernel:  1-wave SEQUENTIAL-SCAN greedy (argmax over sorted list
//                      == forward scan), rows streamed HBM->LDS with counted
//                      vmcnt prefetch; emits 300 rois (zero-padded).
// ---------------------------------------------------------------------------

namespace {

constexpr int kNTot = 3133440;   // total anchors across levels
constexpr int kB1 = 2359296;     // 512*512*9
constexpr int kB2 = 2949120;     // + 256*256*9
constexpr int kB3 = 3096576;     // + 128*128*9
constexpr int kNBins = 8192;
constexpr int kCap = 8192;       // candidate buffer capacity (pow2 for bitonic)
constexpr int kTopK = 4000;
constexpr int kNPad = 4096;      // padded candidate count for 64-bit words
constexpr int kNRois = 300;
constexpr int kChunk = 32;       // greedy scan chunk (rows per stage)
constexpr int kNChunks = kTopK / kChunk;  // 125

// ws byte offsets
constexpr size_t kOffHist    = 0;        // 8192 * u32 = 32768
constexpr size_t kOffCounter = 32768;    // u32
constexpr size_t kOffSel     = 32772;    // u32
constexpr size_t kOffSup     = 32776;    // 64 * u64 = 512  (8-aligned)
constexpr size_t kOffKeys    = 65536;    // 8192 * u64 = 65536
constexpr size_t kOffBoxes   = 131072;   // 4096 * float4 = 65536
constexpr size_t kOffRows    = 212992;   // 4000 * 64 * u64 = 2048000
// total ws usage: 2,260,992 bytes

// NOTE: layout (h,w,9,6) is fully linear in anchor index a: score = x[6a],
// deltas = x[6a+2..5]; anchors (h,w,9,4): anchor a at anc[4a].

struct LevelPick { const float* x; unsigned local; };

__device__ __forceinline__ LevelPick pick_level(unsigned g, const float* x1, const float* x2,
                                                const float* x3, const float* x4) {
  LevelPick p;
  if (g < (unsigned)kB1)      { p.x = x1; p.local = g; }
  else if (g < (unsigned)kB2) { p.x = x2; p.local = g - kB1; }
  else if (g < (unsigned)kB3) { p.x = x3; p.local = g - kB2; }
  else                        { p.x = x4; p.local = g - kB3; }
  return p;
}

__device__ __forceinline__ int score_bin(float s) {
  int b = (int)(s * (float)kNBins);
  return min(max(b, 0), kNBins - 1);
}

// Load 4 consecutive anchors' scores with aligned float4s (anchor group g0%4==0):
// floats f[0..23] hold scores at offsets {0,6,12,18}.
__device__ __forceinline__ void load_scores4(const float* x, unsigned local0, float s[4]) {
  const float4* p = (const float4*)(x + (size_t)local0 * 6);
  float4 q0 = p[0], q1 = p[1], q3 = p[3], q4 = p[4];
  s[0] = q0.x; s[1] = q1.z; s[2] = q3.x; s[3] = q4.z;
}

__global__ void hist_kernel(const float* __restrict__ x1, const float* __restrict__ x2,
                            const float* __restrict__ x3, const float* __restrict__ x4,
                            unsigned* __restrict__ hist) {
  int t = blockIdx.x * blockDim.x + threadIdx.x;
  if (t >= kNTot / 4) return;
  unsigned g0 = (unsigned)t * 4;
  LevelPick lp = pick_level(g0, x1, x2, x3, x4);
  float s[4];
  load_scores4(lp.x, lp.local, s);
  #pragma unroll
  for (int i = 0; i < 4; ++i) atomicAdd(&hist[score_bin(s[i])], 1u);
}

// 1 block, 256 threads: find smallest bin B with suffix-count >= kTopK.
__global__ void select_kernel(const unsigned* __restrict__ hist, unsigned* __restrict__ sel) {
  __shared__ unsigned csum[256];
  unsigned t = 0;
  int c0 = threadIdx.x * 32;
  for (int b = c0; b < c0 + 32; ++b) t += hist[b];
  csum[threadIdx.x] = t;
  __syncthreads();
  if (threadIdx.x == 0) {
    unsigned acc = 0;
    int B = 0;
    int c;
    for (c = 255; c >= 0; --c) {
      if (acc + csum[c] >= (unsigned)kTopK) break;
      acc += csum[c];
    }
    if (c >= 0) {
      int b;
      for (b = c * 32 + 31; b >= c * 32; --b) {
        acc += hist[b];
        if (acc >= (unsigned)kTopK) break;
      }
      B = max(b, 0);
    }
    sel[0] = (unsigned)B;
  }
}

__global__ void compact_kernel(const float* __restrict__ x1, const float* __restrict__ x2,
                               const float* __restrict__ x3, const float* __restrict__ x4,
                               const unsigned* __restrict__ sel,
                               unsigned* __restrict__ counter,
                               unsigned long long* __restrict__ keys) {
  int t = blockIdx.x * blockDim.x + threadIdx.x;
  if (t >= kNTot / 4) return;
  unsigned g0 = (unsigned)t * 4;
  LevelPick lp = pick_level(g0, x1, x2, x3, x4);
  float s[4];
  load_scores4(lp.x, lp.local, s);
  unsigned B = sel[0];
  #pragma unroll
  for (int i = 0; i < 4; ++i) {
    if ((unsigned)score_bin(s[i]) >= B) {
      unsigned pos = atomicAdd(counter, 1u);
      if (pos < (unsigned)kCap) {
        unsigned g = g0 + i;
        // key: high 32 = score bits (scores >= 0 so monotonic), low 32 = ~index
        // -> sorting keys DESC gives (score desc, index asc) == lax.top_k order.
        keys[pos] = ((unsigned long long)__float_as_uint(s[i]) << 32) |
                    (unsigned long long)(0xFFFFFFFFu - g);
      }
    }
  }
}

__device__ __forceinline__ void decode_box(unsigned g,
                                           const float* __restrict__ x1, const float* __restrict__ x2,
                                           const float* __restrict__ x3, const float* __restrict__ x4,
                                           const float* __restrict__ a1, const float* __restrict__ a2,
                                           const float* __restrict__ a3, const float* __restrict__ a4,
                                           float4* box) {
  const float* x;
  const float* anc;
  unsigned local;
  if (g < (unsigned)kB1)      { x = x1; anc = a1; local = g; }
  else if (g < (unsigned)kB2) { x = x2; anc = a2; local = g - kB1; }
  else if (g < (unsigned)kB3) { x = x3; anc = a3; local = g - kB2; }
  else                        { x = x4; anc = a4; local = g - kB3; }
  const float* xe = x + (size_t)local * 6;
  float dy = xe[2], dx = xe[3], dh = xe[4], dwv = xe[5];
  const float* ae = anc + (size_t)local * 4;
  float ay1 = ae[0], ax1 = ae[1], ay2 = ae[2], ax2 = ae[3];
  float ah = ay2 - ay1;
  float aw = ax2 - ax1;
  float acy = ay1 + 0.5f * ah;
  float acx = ax1 + 0.5f * aw;
  float cy = acy + dy * ah;
  float cx = acx + dx * aw;
  float bh = ah * expf(dh);
  float bw = aw * expf(dwv);
  box->x = fminf(fmaxf(cy - 0.5f * bh, 0.0f), 2048.0f);
  box->y = fminf(fmaxf(cx - 0.5f * bw, 0.0f), 2048.0f);
  box->z = fminf(fmaxf(cy + 0.5f * bh, 0.0f), 2048.0f);
  box->w = fminf(fmaxf(cx + 0.5f * bw, 0.0f), 2048.0f);
}

// 1 block, 1024 threads, 64KB dynamic LDS. Bitonic sort 8192 keys desc,
// decode first 4000 into boxes (padded to 4096 zeros), emit sup-init words
// (bit set == inert: score < 0.5 or padding).
__global__ void sortdecode_kernel(const unsigned long long* __restrict__ keys,
                                  const unsigned* __restrict__ counter,
                                  const float* __restrict__ x1, const float* __restrict__ x2,
                                  const float* __restrict__ x3, const float* __restrict__ x4,
                                  const float* __restrict__ a1, const float* __restrict__ a2,
                                  const float* __restrict__ a3, const float* __restrict__ a4,
                                  float4* __restrict__ boxes,
                                  unsigned long long* __restrict__ supinit) {
  extern __shared__ unsigned long long skeys[];
  unsigned n = min(*counter, (unsigned)kCap);
  int tid = threadIdx.x;
  for (int i = tid; i < kCap; i += 1024) skeys[i] = (i < (int)n) ? keys[i] : 0ull;
  __syncthreads();
  for (unsigned k = 2; k <= (unsigned)kCap; k <<= 1) {
    for (unsigned j = k >> 1; j > 0; j >>= 1) {
      for (unsigned i = tid; i < (unsigned)kCap; i += 1024) {
        unsigned ixj = i ^ j;
        if (ixj > i) {
          unsigned long long va = skeys[i], vb = skeys[ixj];
          bool up = ((i & k) == 0);  // descending network
          if (up ? (va < vb) : (va > vb)) { skeys[i] = vb; skeys[ixj] = va; }
        }
      }
      __syncthreads();
    }
  }
  // ranks i handled by consecutive lanes of a wave -> ballot gives sup word.
  for (int i = tid; i < kNPad; i += 1024) {
    unsigned long long key = (i < kTopK) ? skeys[i] : 0ull;
    float4 box = make_float4(0.f, 0.f, 0.f, 0.f);
    float sc = 0.f;
    if (key != 0ull) {
      unsigned sb = (unsigned)(key >> 32);
      unsigned g = 0xFFFFFFFFu - (unsigned)(key & 0xFFFFFFFFull);
      sc = __uint_as_float(sb);
      if (g < (unsigned)kNTot) {
        decode_box(g, x1, x2, x3, x4, a1, a2, a3, a4, &box);
      }
    }
    boxes[i] = box;
    unsigned long long dead = __ballot(!(sc >= 0.5f));
    if ((threadIdx.x & 63) == 0) supinit[i >> 6] = dead;
  }
}

// One wave per 64-column word: rows[i][w] bit j = (IoU(box_i, box_{64w+j}) > 0.5)
__global__ void iou_kernel(const float4* __restrict__ boxes,
                           unsigned long long* __restrict__ rows) {
  int wave = (blockIdx.x * blockDim.x + threadIdx.x) >> 6;
  int lane = threadIdx.x & 63;
  if (wave >= kTopK * 64) return;
  int row = wave >> 6;
  int wc = wave & 63;
  int j = wc * 64 + lane;
  float4 bi = boxes[row];
  float4 bj = boxes[j];
  float yy1 = fmaxf(bi.x, bj.x);
  float xx1 = fmaxf(bi.y, bj.y);
  float yy2 = fminf(bi.z, bj.z);
  float xx2 = fminf(bi.w, bj.w);
  float inter = fmaxf(yy2 - yy1, 0.0f) * fmaxf(xx2 - xx1, 0.0f);
  float ar1 = (bi.z - bi.x) * (bi.w - bi.y);
  float ar2 = (bj.z - bj.x) * (bj.w - bj.y);
  float iou = inter / (ar1 + ar2 - inter + 1e-9f);
  unsigned long long m = __ballot(iou > 0.5f);
  if (lane == 0) rows[(size_t)row * 64 + wc] = m;
}

__device__ __forceinline__ void glds16(const void* g, void* l) {
  __builtin_amdgcn_global_load_lds(
      (const __attribute__((address_space(1))) unsigned int*)g,
      (__attribute__((address_space(3))) unsigned int*)l, 16, 0, 0);
}

// Stage one chunk (32 rows x 512B = 16KB) of the rows table into LDS.
// 16 x global_load_lds dwordx4: instr i covers bytes [i*1024, i*1024+1024).
__device__ __forceinline__ void stage_chunk(const unsigned long long* rows, int chunk,
                                            unsigned long long* dst, int lane) {
  const char* src = (const char*)(rows + (size_t)chunk * kChunk * 64);
  char* d = (char*)dst;
  #pragma unroll
  for (int i = 0; i < 16; ++i) {
    glds16(src + i * 1024 + lane * 16, d + i * 1024);
  }
}

// 1 wave. Greedy argmax over a score-desc-sorted list == forward sequential
// scan: visit ranks 0..3999 in order; an unsuppressed rank IS the next pick.
// Row addresses are therefore sequential -> double-buffered LDS staging with
// counted vmcnt fully hides HBM latency. Lane l holds sup word l (64 ranks).
__global__ void greedy_kernel(const float4* __restrict__ boxes,
                              const unsigned long long* __restrict__ supinit,
                              const unsigned long long* __restrict__ rows,
                              float* __restrict__ out) {
  __shared__ unsigned long long rowbuf[2][kChunk * 64];  // 2 x 16KB
  __shared__ int picksLds[kNRois];
  const int lane = threadIdx.x;
  unsigned long long sup = supinit[lane];
  stage_chunk(rows, 0, &rowbuf[0][0], lane);
  stage_chunk(rows, 1, &rowbuf[1][0], lane);
  int count = 0;
  int curw = -1;
  unsigned long long curword = 0;
  for (int c = 0; c < kNChunks; ++c) {
    if (c + 1 < kNChunks) {
      asm volatile("s_waitcnt vmcnt(16)" ::: "memory");   // chunk c arrived
    } else {
      asm volatile("s_waitcnt vmcnt(0)" ::: "memory");
    }
    __builtin_amdgcn_sched_barrier(0);
    const int b = c & 1;
    unsigned long long rowcur = rowbuf[b][lane];  // slot 0 (1-deep ds pipeline)
    const int base = c * kChunk;
    for (int i = 0; i < kChunk; ++i) {
      unsigned long long rownext = (i + 1 < kChunk) ? rowbuf[b][(i + 1) * 64 + lane] : 0ull;
      const int r = base + i;
      const int w = r >> 6;
      if (w != curw) { curw = w; curword = __shfl(sup, w); }
      if (((curword >> (r & 63)) & 1ull) == 0ull) {
        // pick rank r
        if (lane == 0) picksLds[count] = r;
        ++count;
        sup |= rowcur;
        curword |= __shfl(rowcur, w) | (1ull << (r & 63));
        if (lane == w) sup |= (1ull << (r & 63));  // self (deg. zero-area boxes)
        if (count == kNRois) break;
      }
      rowcur = rownext;
    }
    if (count == kNRois) break;
    if (c + 2 < kNChunks) stage_chunk(rows, c + 2, &rowbuf[b][0], lane);
    if (__ballot(~sup != 0ull) == 0ull) break;  // nothing alive anywhere ahead
  }
  __syncthreads();
  for (int p = lane; p < kNRois; p += 64) {
    float4 bx = make_float4(0.f, 0.f, 0.f, 0.f);
    if (p < count) bx = boxes[picksLds[p]];
    ((float4*)out)[p] = bx;  // zero-pads the tail; replaces out memset
  }
}

}  // namespace

extern "C" void kernel_launch(void* const* d_in, const int* in_sizes, int n_in,
                              void* d_out, int out_size, void* d_ws, size_t ws_size,
                              hipStream_t stream) {
  const float* x1 = (const float*)d_in[0];
  const float* a1 = (const float*)d_in[1];
  const float* x2 = (const float*)d_in[2];
  const float* a2 = (const float*)d_in[3];
  const float* x3 = (const float*)d_in[4];
  const float* a3 = (const float*)d_in[5];
  const float* x4 = (const float*)d_in[6];
  const float* a4 = (const float*)d_in[7];

  char* ws = (char*)d_ws;
  unsigned* hist = (unsigned*)(ws + kOffHist);
  unsigned* counter = (unsigned*)(ws + kOffCounter);
  unsigned* sel = (unsigned*)(ws + kOffSel);
  unsigned long long* supinit = (unsigned long long*)(ws + kOffSup);
  unsigned long long* keys = (unsigned long long*)(ws + kOffKeys);
  float4* boxes = (float4*)(ws + kOffBoxes);
  unsigned long long* rows = (unsigned long long*)(ws + kOffRows);
  float* out = (float*)d_out;

  // per-call re-init (harness does not re-poison between replays)
  hipMemsetAsync(ws, 0, kOffSup, stream);  // hist + counter + sel

  int blocks4 = (kNTot / 4 + 255) / 256;  // 3060
  hist_kernel<<<blocks4, 256, 0, stream>>>(x1, x2, x3, x4, hist);
  select_kernel<<<1, 256, 0, stream>>>(hist, sel);
  compact_kernel<<<blocks4, 256, 0, stream>>>(x1, x2, x3, x4, sel, counter, keys);
  sortdecode_kernel<<<1, 1024, kCap * sizeof(unsigned long long), stream>>>(
      keys, counter, x1, x2, x3, x4, a1, a2, a3, a4, boxes, supinit);
  iou_kernel<<<(kTopK * 64 * 64) / 256, 256, 0, stream>>>(boxes, rows);
  greedy_kernel<<<1, 64, 0, stream>>>(boxes, supinit, rows, out);
}

// Round 3
// 310.860 us; speedup vs baseline: 1.6055x; 1.2501x over previous
//
#include <hip/hip_runtime.h>

// ---------------------------------------------------------------------------
// PyramidNSMLayer: 4-level anchor decode + top-4000 selection + greedy NMS.
//
// Pipeline (all on `stream`, graph-capturable, deterministic):
//   1. memset hist/counter (ws)
//   2. hist_kernel:    8192-bin histogram of all 3,133,440 scores (4/thread, float4)
//   3. select_kernel:  smallest bin B with suffix-count >= 4000
//   4. compact_kernel: gather (score,index) keys for bin >= B  (~4.4K items)
//   5. rank_kernel:    rank-by-counting exact sort (keys distinct): 32 blocks,
//                      each thread counts #greater over LDS-staged keys
//   6. decode_kernel:  decode top-4000 ranks into boxes + supinit bitmask
//   7. iou_kernel:     4000 x 4096 bitmask of IoU > 0.5
//   8. greedy_kernel:  1-wave SEQUENTIAL-SCAN greedy (argmax over sorted list
//                      == forward scan), rows streamed HBM->LDS with counted
//                      vmcnt prefetch; emits 300 rois (zero-padded).
// ---------------------------------------------------------------------------

namespace {

constexpr int kNTot = 3133440;   // total anchors across levels
constexpr int kB1 = 2359296;     // 512*512*9
constexpr int kB2 = 2949120;     // + 256*256*9
constexpr int kB3 = 3096576;     // + 128*128*9
constexpr int kNBins = 8192;
constexpr int kCap = 8192;       // candidate buffer capacity
constexpr int kTopK = 4000;
constexpr int kNPad = 4096;      // padded candidate count for 64-bit words
constexpr int kNRois = 300;
constexpr int kChunk = 32;       // greedy scan chunk (rows per stage)
constexpr int kNChunks = kTopK / kChunk;  // 125

// ws byte offsets
constexpr size_t kOffSorted  = 0;        // 4096 * u64 = 32768 (aliases hist!)
constexpr size_t kOffHist    = 0;        // 8192 * u32 = 32768 (dead after compact)
constexpr size_t kOffCounter = 32768;    // u32
constexpr size_t kOffSel     = 32772;    // u32
constexpr size_t kOffSup     = 32776;    // 64 * u64 = 512  (8-aligned)
constexpr size_t kOffKeys    = 65536;    // 8192 * u64 = 65536
constexpr size_t kOffBoxes   = 131072;   // 4096 * float4 = 65536
constexpr size_t kOffRows    = 212992;   // 4000 * 64 * u64 = 2048000
// total ws usage: 2,260,992 bytes

// NOTE: layout (h,w,9,6) is fully linear in anchor index a: score = x[6a],
// deltas = x[6a+2..5]; anchors (h,w,9,4): anchor a at anc[4a].

struct LevelPick { const float* x; unsigned local; };

__device__ __forceinline__ LevelPick pick_level(unsigned g, const float* x1, const float* x2,
                                                const float* x3, const float* x4) {
  LevelPick p;
  if (g < (unsigned)kB1)      { p.x = x1; p.local = g; }
  else if (g < (unsigned)kB2) { p.x = x2; p.local = g - kB1; }
  else if (g < (unsigned)kB3) { p.x = x3; p.local = g - kB2; }
  else                        { p.x = x4; p.local = g - kB3; }
  return p;
}

__device__ __forceinline__ int score_bin(float s) {
  int b = (int)(s * (float)kNBins);
  return min(max(b, 0), kNBins - 1);
}

// Load 4 consecutive anchors' scores with aligned float4s (anchor group g0%4==0):
// floats f[0..23] hold scores at offsets {0,6,12,18}.
__device__ __forceinline__ void load_scores4(const float* x, unsigned local0, float s[4]) {
  const float4* p = (const float4*)(x + (size_t)local0 * 6);
  float4 q0 = p[0], q1 = p[1], q3 = p[3], q4 = p[4];
  s[0] = q0.x; s[1] = q1.z; s[2] = q3.x; s[3] = q4.z;
}

__global__ void hist_kernel(const float* __restrict__ x1, const float* __restrict__ x2,
                            const float* __restrict__ x3, const float* __restrict__ x4,
                            unsigned* __restrict__ hist) {
  int t = blockIdx.x * blockDim.x + threadIdx.x;
  if (t >= kNTot / 4) return;
  unsigned g0 = (unsigned)t * 4;
  LevelPick lp = pick_level(g0, x1, x2, x3, x4);
  float s[4];
  load_scores4(lp.x, lp.local, s);
  #pragma unroll
  for (int i = 0; i < 4; ++i) atomicAdd(&hist[score_bin(s[i])], 1u);
}

// 1 block, 256 threads: find smallest bin B with suffix-count >= kTopK.
__global__ void select_kernel(const unsigned* __restrict__ hist, unsigned* __restrict__ sel) {
  __shared__ unsigned csum[256];
  unsigned t = 0;
  int c0 = threadIdx.x * 32;
  for (int b = c0; b < c0 + 32; ++b) t += hist[b];
  csum[threadIdx.x] = t;
  __syncthreads();
  if (threadIdx.x == 0) {
    unsigned acc = 0;
    int B = 0;
    int c;
    for (c = 255; c >= 0; --c) {
      if (acc + csum[c] >= (unsigned)kTopK) break;
      acc += csum[c];
    }
    if (c >= 0) {
      int b;
      for (b = c * 32 + 31; b >= c * 32; --b) {
        acc += hist[b];
        if (acc >= (unsigned)kTopK) break;
      }
      B = max(b, 0);
    }
    sel[0] = (unsigned)B;
  }
}

__global__ void compact_kernel(const float* __restrict__ x1, const float* __restrict__ x2,
                               const float* __restrict__ x3, const float* __restrict__ x4,
                               const unsigned* __restrict__ sel,
                               unsigned* __restrict__ counter,
                               unsigned long long* __restrict__ keys) {
  int t = blockIdx.x * blockDim.x + threadIdx.x;
  if (t >= kNTot / 4) return;
  unsigned g0 = (unsigned)t * 4;
  LevelPick lp = pick_level(g0, x1, x2, x3, x4);
  float s[4];
  load_scores4(lp.x, lp.local, s);
  unsigned B = sel[0];
  #pragma unroll
  for (int i = 0; i < 4; ++i) {
    if ((unsigned)score_bin(s[i]) >= B) {
      unsigned pos = atomicAdd(counter, 1u);
      if (pos < (unsigned)kCap) {
        unsigned g = g0 + i;
        // key: high 32 = score bits (scores >= 0 so monotonic), low 32 = ~index
        // -> rank by key DESC gives (score desc, index asc) == lax.top_k order.
        keys[pos] = ((unsigned long long)__float_as_uint(s[i]) << 32) |
                    (unsigned long long)(0xFFFFFFFFu - g);
      }
    }
  }
}

// Exact sort by rank-counting: keys are distinct, so rank_i = #{j: key_j>key_i}
// is a bijection onto 0..n-1, independent of the (nondeterministic) atomic
// compaction order. 32 blocks x 256 threads; all keys staged in LDS; each
// thread owns one i and loops all j (uniform addr -> LDS broadcast).
__global__ void rank_kernel(const unsigned long long* __restrict__ keys,
                            const unsigned* __restrict__ counter,
                            unsigned long long* __restrict__ sorted) {
  extern __shared__ unsigned long long lk[];
  int n = min((int)*counter, kCap);
  int npad = (n + 3) & ~3;
  for (int i = threadIdx.x; i < npad; i += 256) lk[i] = (i < n) ? keys[i] : 0ull;
  __syncthreads();
  int i = blockIdx.x * 256 + threadIdx.x;
  unsigned long long ki = (i < n) ? lk[i] : ~0ull;  // ~0: nothing ranks above
  int rank = 0;
  const ulonglong2* p2 = (const ulonglong2*)lk;
  for (int j = 0; j < (npad >> 1); j += 2) {
    ulonglong2 a = p2[j];
    ulonglong2 b = p2[j + 1];
    rank += (int)(a.x > ki) + (int)(a.y > ki) + (int)(b.x > ki) + (int)(b.y > ki);
  }
  if (i < n && rank < kNPad) sorted[rank] = ki;
}

__device__ __forceinline__ void decode_box(unsigned g,
                                           const float* __restrict__ x1, const float* __restrict__ x2,
                                           const float* __restrict__ x3, const float* __restrict__ x4,
                                           const float* __restrict__ a1, const float* __restrict__ a2,
                                           const float* __restrict__ a3, const float* __restrict__ a4,
                                           float4* box) {
  const float* x;
  const float* anc;
  unsigned local;
  if (g < (unsigned)kB1)      { x = x1; anc = a1; local = g; }
  else if (g < (unsigned)kB2) { x = x2; anc = a2; local = g - kB1; }
  else if (g < (unsigned)kB3) { x = x3; anc = a3; local = g - kB2; }
  else                        { x = x4; anc = a4; local = g - kB3; }
  const float* xe = x + (size_t)local * 6;
  float dy = xe[2], dx = xe[3], dh = xe[4], dwv = xe[5];
  const float* ae = anc + (size_t)local * 4;
  float ay1 = ae[0], ax1 = ae[1], ay2 = ae[2], ax2 = ae[3];
  float ah = ay2 - ay1;
  float aw = ax2 - ax1;
  float acy = ay1 + 0.5f * ah;
  float acx = ax1 + 0.5f * aw;
  float cy = acy + dy * ah;
  float cx = acx + dx * aw;
  float bh = ah * expf(dh);
  float bw = aw * expf(dwv);
  box->x = fminf(fmaxf(cy - 0.5f * bh, 0.0f), 2048.0f);
  box->y = fminf(fmaxf(cx - 0.5f * bw, 0.0f), 2048.0f);
  box->z = fminf(fmaxf(cy + 0.5f * bh, 0.0f), 2048.0f);
  box->w = fminf(fmaxf(cx + 0.5f * bw, 0.0f), 2048.0f);
}

// 16 blocks x 256: decode rank r's box (zero beyond top-k / count), emit
// supinit words (bit set == inert: score < 0.5 or padding).
__global__ void decode_kernel(const unsigned long long* __restrict__ sorted,
                              const unsigned* __restrict__ counter,
                              const float* __restrict__ x1, const float* __restrict__ x2,
                              const float* __restrict__ x3, const float* __restrict__ x4,
                              const float* __restrict__ a1, const float* __restrict__ a2,
                              const float* __restrict__ a3, const float* __restrict__ a4,
                              float4* __restrict__ boxes,
                              unsigned long long* __restrict__ supinit) {
  int r = blockIdx.x * 256 + threadIdx.x;
  int n = min((int)*counter, kTopK);
  unsigned long long key = (r < n) ? sorted[r] : 0ull;
  float4 box = make_float4(0.f, 0.f, 0.f, 0.f);
  float sc = 0.f;
  if (key != 0ull) {
    sc = __uint_as_float((unsigned)(key >> 32));
    unsigned g = 0xFFFFFFFFu - (unsigned)(key & 0xFFFFFFFFull);
    if (g < (unsigned)kNTot) decode_box(g, x1, x2, x3, x4, a1, a2, a3, a4, &box);
  }
  boxes[r] = box;
  unsigned long long dead = __ballot(!(sc >= 0.5f));
  if ((threadIdx.x & 63) == 0) supinit[r >> 6] = dead;
}

// One wave per 64-column word: rows[i][w] bit j = (IoU(box_i, box_{64w+j}) > 0.5)
__global__ void iou_kernel(const float4* __restrict__ boxes,
                           unsigned long long* __restrict__ rows) {
  int wave = (blockIdx.x * blockDim.x + threadIdx.x) >> 6;
  int lane = threadIdx.x & 63;
  if (wave >= kTopK * 64) return;
  int row = wave >> 6;
  int wc = wave & 63;
  int j = wc * 64 + lane;
  float4 bi = boxes[row];
  float4 bj = boxes[j];
  float yy1 = fmaxf(bi.x, bj.x);
  float xx1 = fmaxf(bi.y, bj.y);
  float yy2 = fminf(bi.z, bj.z);
  float xx2 = fminf(bi.w, bj.w);
  float inter = fmaxf(yy2 - yy1, 0.0f) * fmaxf(xx2 - xx1, 0.0f);
  float ar1 = (bi.z - bi.x) * (bi.w - bi.y);
  float ar2 = (bj.z - bj.x) * (bj.w - bj.y);
  float iou = inter / (ar1 + ar2 - inter + 1e-9f);
  unsigned long long m = __ballot(iou > 0.5f);
  if (lane == 0) rows[(size_t)row * 64 + wc] = m;
}

__device__ __forceinline__ void glds16(const void* g, void* l) {
  __builtin_amdgcn_global_load_lds(
      (const __attribute__((address_space(1))) unsigned int*)g,
      (__attribute__((address_space(3))) unsigned int*)l, 16, 0, 0);
}

// Stage one chunk (32 rows x 512B = 16KB) of the rows table into LDS.
// 16 x global_load_lds dwordx4: instr i covers bytes [i*1024, i*1024+1024).
__device__ __forceinline__ void stage_chunk(const unsigned long long* rows, int chunk,
                                            unsigned long long* dst, int lane) {
  const char* src = (const char*)(rows + (size_t)chunk * kChunk * 64);
  char* d = (char*)dst;
  #pragma unroll
  for (int i = 0; i < 16; ++i) {
    glds16(src + i * 1024 + lane * 16, d + i * 1024);
  }
}

// 1 wave. Greedy argmax over a score-desc-sorted list == forward sequential
// scan: visit ranks 0..3999 in order; an unsuppressed rank IS the next pick.
// Row addresses are therefore sequential -> double-buffered LDS staging with
// counted vmcnt fully hides HBM latency. Lane l holds sup word l (64 ranks).
__global__ void greedy_kernel(const float4* __restrict__ boxes,
                              const unsigned long long* __restrict__ supinit,
                              const unsigned long long* __restrict__ rows,
                              float* __restrict__ out) {
  __shared__ unsigned long long rowbuf[2][kChunk * 64];  // 2 x 16KB
  __shared__ int picksLds[kNRois];
  const int lane = threadIdx.x;
  unsigned long long sup = supinit[lane];
  stage_chunk(rows, 0, &rowbuf[0][0], lane);
  stage_chunk(rows, 1, &rowbuf[1][0], lane);
  int count = 0;
  int curw = -1;
  unsigned long long curword = 0;
  for (int c = 0; c < kNChunks; ++c) {
    if (c + 1 < kNChunks) {
      asm volatile("s_waitcnt vmcnt(16)" ::: "memory");   // chunk c arrived
    } else {
      asm volatile("s_waitcnt vmcnt(0)" ::: "memory");
    }
    __builtin_amdgcn_sched_barrier(0);
    const int b = c & 1;
    unsigned long long rowcur = rowbuf[b][lane];  // slot 0 (1-deep ds pipeline)
    const int base = c * kChunk;
    for (int i = 0; i < kChunk; ++i) {
      unsigned long long rownext = (i + 1 < kChunk) ? rowbuf[b][(i + 1) * 64 + lane] : 0ull;
      const int r = base + i;
      const int w = r >> 6;
      if (w != curw) { curw = w; curword = __shfl(sup, w); }
      if (((curword >> (r & 63)) & 1ull) == 0ull) {
        // pick rank r
        if (lane == 0) picksLds[count] = r;
        ++count;
        sup |= rowcur;
        curword |= __shfl(rowcur, w) | (1ull << (r & 63));
        if (lane == w) sup |= (1ull << (r & 63));  // self (deg. zero-area boxes)
        if (count == kNRois) break;
      }
      rowcur = rownext;
    }
    if (count == kNRois) break;
    if (c + 2 < kNChunks) stage_chunk(rows, c + 2, &rowbuf[b][0], lane);
    if (__ballot(~sup != 0ull) == 0ull) break;  // nothing alive anywhere ahead
  }
  __syncthreads();
  for (int p = lane; p < kNRois; p += 64) {
    float4 bx = make_float4(0.f, 0.f, 0.f, 0.f);
    if (p < count) bx = boxes[picksLds[p]];
    ((float4*)out)[p] = bx;  // zero-pads the tail; replaces out memset
  }
}

}  // namespace

extern "C" void kernel_launch(void* const* d_in, const int* in_sizes, int n_in,
                              void* d_out, int out_size, void* d_ws, size_t ws_size,
                              hipStream_t stream) {
  const float* x1 = (const float*)d_in[0];
  const float* a1 = (const float*)d_in[1];
  const float* x2 = (const float*)d_in[2];
  const float* a2 = (const float*)d_in[3];
  const float* x3 = (const float*)d_in[4];
  const float* a3 = (const float*)d_in[5];
  const float* x4 = (const float*)d_in[6];
  const float* a4 = (const float*)d_in[7];

  char* ws = (char*)d_ws;
  unsigned* hist = (unsigned*)(ws + kOffHist);
  unsigned long long* sorted = (unsigned long long*)(ws + kOffSorted);  // aliases hist
  unsigned* counter = (unsigned*)(ws + kOffCounter);
  unsigned* sel = (unsigned*)(ws + kOffSel);
  unsigned long long* supinit = (unsigned long long*)(ws + kOffSup);
  unsigned long long* keys = (unsigned long long*)(ws + kOffKeys);
  float4* boxes = (float4*)(ws + kOffBoxes);
  unsigned long long* rows = (unsigned long long*)(ws + kOffRows);
  float* out = (float*)d_out;

  // per-call re-init (harness does not re-poison between replays)
  hipMemsetAsync(ws, 0, kOffSup, stream);  // hist + counter + sel

  int blocks4 = (kNTot / 4 + 255) / 256;  // 3060
  hist_kernel<<<blocks4, 256, 0, stream>>>(x1, x2, x3, x4, hist);
  select_kernel<<<1, 256, 0, stream>>>(hist, sel);
  compact_kernel<<<blocks4, 256, 0, stream>>>(x1, x2, x3, x4, sel, counter, keys);
  rank_kernel<<<kCap / 256, 256, kCap * sizeof(unsigned long long), stream>>>(
      keys, counter, sorted);
  decode_kernel<<<kNPad / 256, 256, 0, stream>>>(
      sorted, counter, x1, x2, x3, x4, a1, a2, a3, a4, boxes, supinit);
  iou_kernel<<<(kTopK * 64 * 64) / 256, 256, 0, stream>>>(boxes, rows);
  greedy_kernel<<<1, 64, 0, stream>>>(boxes, supinit, rows, out);
}

// Round 4
// 252.886 us; speedup vs baseline: 1.9736x; 1.2292x over previous
//
#include <hip/hip_runtime.h>

// ---------------------------------------------------------------------------
// PyramidNSMLayer: 4-level anchor decode + top-4000 selection + greedy NMS.
//
// Pipeline (all on `stream`, graph-capturable, deterministic):
//   1. memset counter/sel (8 B)
//   2. hist_kernel:    per-block LDS 1024-bin histogram -> partials (no
//                      global atomics; old version spent 117us on 3.1M
//                      device-scope atomicAdds, WRITE_SIZE 95MB)
//   3. select_kernel:  reduce 128 partials, smallest bin B w/ suffix >= 4000
//   4. compact_kernel: gather (score,index) keys for bin >= B  (~7K items)
//   5. rank_kernel:    rank-by-counting exact sort (keys distinct)
//   6. decode_kernel:  decode top-4000 ranks into boxes + supinit bitmask
//   7. iou_kernel:     upper-triangle 4000 x 4096 bitmask of IoU > 0.5
//                      (lower-triangle words are never consumed by greedy)
//   8. greedy_kernel:  1-wave SEQUENTIAL-SCAN greedy (argmax over sorted list
//                      == forward scan), rows streamed HBM->LDS with counted
//                      vmcnt prefetch; emits 300 rois (zero-padded).
// ---------------------------------------------------------------------------

namespace {

constexpr int kNTot = 3133440;   // total anchors across levels
constexpr int kB1 = 2359296;     // 512*512*9
constexpr int kB2 = 2949120;     // + 256*256*9
constexpr int kB3 = 3096576;     // + 128*128*9
constexpr int kNBins = 1024;
constexpr int kNParts = 128;     // histogram partial blocks
constexpr int kCap = 8192;       // candidate buffer capacity
constexpr int kTopK = 4000;
constexpr int kNPad = 4096;      // padded candidate count for 64-bit words
constexpr int kNRois = 300;
constexpr int kChunk = 32;       // greedy scan chunk (rows per stage)
constexpr int kNChunks = kTopK / kChunk;  // 125

// ws byte offsets
constexpr size_t kOffPart    = 0;        // 128 * 1024 * u32 = 524288
constexpr size_t kOffCounter = 524288;   // u32
constexpr size_t kOffSel     = 524292;   // u32
constexpr size_t kOffSup     = 524296;   // 64 * u64 = 512
constexpr size_t kOffSorted  = 525312;   // 4096 * u64 = 32768
constexpr size_t kOffKeys    = 558080;   // 8192 * u64 = 65536
constexpr size_t kOffBoxes   = 623616;   // 4096 * float4 = 65536
constexpr size_t kOffRows    = 689152;   // 4000 * 64 * u64 = 2048000
// total ws usage: 2,737,152 bytes

// NOTE: layout (h,w,9,6) is fully linear in anchor index a: score = x[6a],
// deltas = x[6a+2..5]; anchors (h,w,9,4): anchor a at anc[4a].

struct LevelPick { const float* x; unsigned local; };

__device__ __forceinline__ LevelPick pick_level(unsigned g, const float* x1, const float* x2,
                                                const float* x3, const float* x4) {
  LevelPick p;
  if (g < (unsigned)kB1)      { p.x = x1; p.local = g; }
  else if (g < (unsigned)kB2) { p.x = x2; p.local = g - kB1; }
  else if (g < (unsigned)kB3) { p.x = x3; p.local = g - kB2; }
  else                        { p.x = x4; p.local = g - kB3; }
  return p;
}

__device__ __forceinline__ int score_bin(float s) {
  int b = (int)(s * (float)kNBins);
  return min(max(b, 0), kNBins - 1);
}

// Load 4 consecutive anchors' scores with aligned float4s (anchor group g0%4==0):
// floats f[0..23] hold scores at offsets {0,6,12,18}.
__device__ __forceinline__ void load_scores4(const float* x, unsigned local0, float s[4]) {
  const float4* p = (const float4*)(x + (size_t)local0 * 6);
  float4 q0 = p[0], q1 = p[1], q3 = p[3], q4 = p[4];
  s[0] = q0.x; s[1] = q1.z; s[2] = q3.x; s[3] = q4.z;
}

// 128 blocks x 512: per-block LDS histogram, plain-store partials.
__global__ void hist_kernel(const float* __restrict__ x1, const float* __restrict__ x2,
                            const float* __restrict__ x3, const float* __restrict__ x4,
                            unsigned* __restrict__ part) {
  __shared__ unsigned h[kNBins];
  for (int i = threadIdx.x; i < kNBins; i += 512) h[i] = 0;
  __syncthreads();
  for (int t = blockIdx.x * 512 + threadIdx.x; t < kNTot / 4; t += kNParts * 512) {
    unsigned g0 = (unsigned)t * 4;
    LevelPick lp = pick_level(g0, x1, x2, x3, x4);
    float s[4];
    load_scores4(lp.x, lp.local, s);
    #pragma unroll
    for (int i = 0; i < 4; ++i) atomicAdd(&h[score_bin(s[i])], 1u);
  }
  __syncthreads();
  for (int i = threadIdx.x; i < kNBins; i += 512)
    part[blockIdx.x * kNBins + i] = h[i];
}

// 1 block, 1024 threads: reduce partials, find smallest bin B with
// suffix-count >= kTopK (breaks after ~2 iterations for uniform data).
__global__ void select_kernel(const unsigned* __restrict__ part, unsigned* __restrict__ sel) {
  __shared__ unsigned csum[kNBins];
  int b = threadIdx.x;
  unsigned t = 0;
  for (int p = 0; p < kNParts; ++p) t += part[p * kNBins + b];
  csum[b] = t;
  __syncthreads();
  if (threadIdx.x == 0) {
    unsigned acc = 0;
    int B = 0;
    for (int bb = kNBins - 1; bb >= 0; --bb) {
      acc += csum[bb];
      if (acc >= (unsigned)kTopK) { B = bb; break; }
    }
    sel[0] = (unsigned)B;
  }
}

__global__ void compact_kernel(const float* __restrict__ x1, const float* __restrict__ x2,
                               const float* __restrict__ x3, const float* __restrict__ x4,
                               const unsigned* __restrict__ sel,
                               unsigned* __restrict__ counter,
                               unsigned long long* __restrict__ keys) {
  int t = blockIdx.x * blockDim.x + threadIdx.x;
  if (t >= kNTot / 4) return;
  unsigned g0 = (unsigned)t * 4;
  LevelPick lp = pick_level(g0, x1, x2, x3, x4);
  float s[4];
  load_scores4(lp.x, lp.local, s);
  unsigned B = sel[0];
  #pragma unroll
  for (int i = 0; i < 4; ++i) {
    if ((unsigned)score_bin(s[i]) >= B) {
      unsigned pos = atomicAdd(counter, 1u);
      if (pos < (unsigned)kCap) {
        unsigned g = g0 + i;
        // key: high 32 = score bits (scores >= 0 so monotonic), low 32 = ~index
        // -> rank by key DESC gives (score desc, index asc) == lax.top_k order.
        keys[pos] = ((unsigned long long)__float_as_uint(s[i]) << 32) |
                    (unsigned long long)(0xFFFFFFFFu - g);
      }
    }
  }
}

// Exact sort by rank-counting: keys are distinct, so rank_i = #{j: key_j>key_i}
// is a bijection onto 0..n-1, independent of the (nondeterministic) atomic
// compaction order. 32 blocks x 256 threads; all keys staged in LDS; each
// thread owns one i and loops all j (uniform addr -> LDS broadcast).
__global__ void rank_kernel(const unsigned long long* __restrict__ keys,
                            const unsigned* __restrict__ counter,
                            unsigned long long* __restrict__ sorted) {
  extern __shared__ unsigned long long lk[];
  int n = min((int)*counter, kCap);
  int npad = (n + 3) & ~3;
  for (int i = threadIdx.x; i < npad; i += 256) lk[i] = (i < n) ? keys[i] : 0ull;
  __syncthreads();
  int i = blockIdx.x * 256 + threadIdx.x;
  unsigned long long ki = (i < n) ? lk[i] : ~0ull;  // ~0: nothing ranks above
  int rank = 0;
  const ulonglong2* p2 = (const ulonglong2*)lk;
  for (int j = 0; j < (npad >> 1); j += 2) {
    ulonglong2 a = p2[j];
    ulonglong2 b = p2[j + 1];
    rank += (int)(a.x > ki) + (int)(a.y > ki) + (int)(b.x > ki) + (int)(b.y > ki);
  }
  if (i < n && rank < kNPad) sorted[rank] = ki;
}

__device__ __forceinline__ void decode_box(unsigned g,
                                           const float* __restrict__ x1, const float* __restrict__ x2,
                                           const float* __restrict__ x3, const float* __restrict__ x4,
                                           const float* __restrict__ a1, const float* __restrict__ a2,
                                           const float* __restrict__ a3, const float* __restrict__ a4,
                                           float4* box) {
  const float* x;
  const float* anc;
  unsigned local;
  if (g < (unsigned)kB1)      { x = x1; anc = a1; local = g; }
  else if (g < (unsigned)kB2) { x = x2; anc = a2; local = g - kB1; }
  else if (g < (unsigned)kB3) { x = x3; anc = a3; local = g - kB2; }
  else                        { x = x4; anc = a4; local = g - kB3; }
  const float* xe = x + (size_t)local * 6;
  float dy = xe[2], dx = xe[3], dh = xe[4], dwv = xe[5];
  const float* ae = anc + (size_t)local * 4;
  float ay1 = ae[0], ax1 = ae[1], ay2 = ae[2], ax2 = ae[3];
  float ah = ay2 - ay1;
  float aw = ax2 - ax1;
  float acy = ay1 + 0.5f * ah;
  float acx = ax1 + 0.5f * aw;
  float cy = acy + dy * ah;
  float cx = acx + dx * aw;
  float bh = ah * expf(dh);
  float bw = aw * expf(dwv);
  box->x = fminf(fmaxf(cy - 0.5f * bh, 0.0f), 2048.0f);
  box->y = fminf(fmaxf(cx - 0.5f * bw, 0.0f), 2048.0f);
  box->z = fminf(fmaxf(cy + 0.5f * bh, 0.0f), 2048.0f);
  box->w = fminf(fmaxf(cx + 0.5f * bw, 0.0f), 2048.0f);
}

// 16 blocks x 256: decode rank r's box (zero beyond top-k / count), emit
// supinit words (bit set == inert: score < 0.5 or padding).
__global__ void decode_kernel(const unsigned long long* __restrict__ sorted,
                              const unsigned* __restrict__ counter,
                              const float* __restrict__ x1, const float* __restrict__ x2,
                              const float* __restrict__ x3, const float* __restrict__ x4,
                              const float* __restrict__ a1, const float* __restrict__ a2,
                              const float* __restrict__ a3, const float* __restrict__ a4,
                              float4* __restrict__ boxes,
                              unsigned long long* __restrict__ supinit) {
  int r = blockIdx.x * 256 + threadIdx.x;
  int n = min((int)*counter, kTopK);
  unsigned long long key = (r < n) ? sorted[r] : 0ull;
  float4 box = make_float4(0.f, 0.f, 0.f, 0.f);
  float sc = 0.f;
  if (key != 0ull) {
    sc = __uint_as_float((unsigned)(key >> 32));
    unsigned g = 0xFFFFFFFFu - (unsigned)(key & 0xFFFFFFFFull);
    if (g < (unsigned)kNTot) decode_box(g, x1, x2, x3, x4, a1, a2, a3, a4, &box);
  }
  boxes[r] = box;
  unsigned long long dead = __ballot(!(sc >= 0.5f));
  if ((threadIdx.x & 63) == 0) supinit[r >> 6] = dead;
}

// One wave per 64-column word: rows[i][w] bit j = (IoU(box_i, box_{64w+j}) > 0.5).
// Upper triangle only (wc >= row/64): greedy never consumes bits for columns
// below the current scan position, so lower words may hold stale junk.
__global__ void iou_kernel(const float4* __restrict__ boxes,
                           unsigned long long* __restrict__ rows) {
  int wave = (blockIdx.x * blockDim.x + threadIdx.x) >> 6;
  int lane = threadIdx.x & 63;
  if (wave >= kTopK * 64) return;
  int row = wave >> 6;
  int wc = wave & 63;
  if (wc < (row >> 6)) return;  // lower-triangle word: never consumed
  int j = wc * 64 + lane;
  float4 bi = boxes[row];
  float4 bj = boxes[j];
  float yy1 = fmaxf(bi.x, bj.x);
  float xx1 = fmaxf(bi.y, bj.y);
  float yy2 = fminf(bi.z, bj.z);
  float xx2 = fminf(bi.w, bj.w);
  float inter = fmaxf(yy2 - yy1, 0.0f) * fmaxf(xx2 - xx1, 0.0f);
  float ar1 = (bi.z - bi.x) * (bi.w - bi.y);
  float ar2 = (bj.z - bj.x) * (bj.w - bj.y);
  float iou = inter / (ar1 + ar2 - inter + 1e-9f);
  unsigned long long m = __ballot(iou > 0.5f);
  if (lane == 0) rows[(size_t)row * 64 + wc] = m;
}

__device__ __forceinline__ void glds16(const void* g, void* l) {
  __builtin_amdgcn_global_load_lds(
      (const __attribute__((address_space(1))) unsigned int*)g,
      (__attribute__((address_space(3))) unsigned int*)l, 16, 0, 0);
}

// Stage one chunk (32 rows x 512B = 16KB) of the rows table into LDS.
// 16 x global_load_lds dwordx4: instr i covers bytes [i*1024, i*1024+1024).
__device__ __forceinline__ void stage_chunk(const unsigned long long* rows, int chunk,
                                            unsigned long long* dst, int lane) {
  const char* src = (const char*)(rows + (size_t)chunk * kChunk * 64);
  char* d = (char*)dst;
  #pragma unroll
  for (int i = 0; i < 16; ++i) {
    glds16(src + i * 1024 + lane * 16, d + i * 1024);
  }
}

// 1 wave. Greedy argmax over a score-desc-sorted list == forward sequential
// scan: visit ranks 0..3999 in order; an unsuppressed rank IS the next pick.
// Row addresses are therefore sequential -> double-buffered LDS staging with
// counted vmcnt fully hides HBM latency. Lane l holds sup word l (64 ranks).
__global__ void greedy_kernel(const float4* __restrict__ boxes,
                              const unsigned long long* __restrict__ supinit,
                              const unsigned long long* __restrict__ rows,
                              float* __restrict__ out) {
  __shared__ unsigned long long rowbuf[2][kChunk * 64];  // 2 x 16KB
  __shared__ int picksLds[kNRois];
  const int lane = threadIdx.x;
  unsigned long long sup = supinit[lane];
  stage_chunk(rows, 0, &rowbuf[0][0], lane);
  stage_chunk(rows, 1, &rowbuf[1][0], lane);
  int count = 0;
  int curw = -1;
  unsigned long long curword = 0;
  for (int c = 0; c < kNChunks; ++c) {
    if (c + 1 < kNChunks) {
      asm volatile("s_waitcnt vmcnt(16)" ::: "memory");   // chunk c arrived
    } else {
      asm volatile("s_waitcnt vmcnt(0)" ::: "memory");
    }
    __builtin_amdgcn_sched_barrier(0);
    const int b = c & 1;
    unsigned long long rowcur = rowbuf[b][lane];  // slot 0 (1-deep ds pipeline)
    const int base = c * kChunk;
    for (int i = 0; i < kChunk; ++i) {
      unsigned long long rownext = (i + 1 < kChunk) ? rowbuf[b][(i + 1) * 64 + lane] : 0ull;
      const int r = base + i;
      const int w = r >> 6;
      if (w != curw) { curw = w; curword = __shfl(sup, w); }
      if (((curword >> (r & 63)) & 1ull) == 0ull) {
        // pick rank r
        if (lane == 0) picksLds[count] = r;
        ++count;
        sup |= rowcur;
        curword |= __shfl(rowcur, w) | (1ull << (r & 63));
        if (lane == w) sup |= (1ull << (r & 63));  // self (deg. zero-area boxes)
        if (count == kNRois) break;
      }
      rowcur = rownext;
    }
    if (count == kNRois) break;
    if (c + 2 < kNChunks) stage_chunk(rows, c + 2, &rowbuf[b][0], lane);
    if (__ballot(~sup != 0ull) == 0ull) break;  // nothing alive anywhere ahead
  }
  __syncthreads();
  for (int p = lane; p < kNRois; p += 64) {
    float4 bx = make_float4(0.f, 0.f, 0.f, 0.f);
    if (p < count) bx = boxes[picksLds[p]];
    ((float4*)out)[p] = bx;  // zero-pads the tail; replaces out memset
  }
}

}  // namespace

extern "C" void kernel_launch(void* const* d_in, const int* in_sizes, int n_in,
                              void* d_out, int out_size, void* d_ws, size_t ws_size,
                              hipStream_t stream) {
  const float* x1 = (const float*)d_in[0];
  const float* a1 = (const float*)d_in[1];
  const float* x2 = (const float*)d_in[2];
  const float* a2 = (const float*)d_in[3];
  const float* x3 = (const float*)d_in[4];
  const float* a3 = (const float*)d_in[5];
  const float* x4 = (const float*)d_in[6];
  const float* a4 = (const float*)d_in[7];

  char* ws = (char*)d_ws;
  unsigned* part = (unsigned*)(ws + kOffPart);
  unsigned* counter = (unsigned*)(ws + kOffCounter);
  unsigned* sel = (unsigned*)(ws + kOffSel);
  unsigned long long* supinit = (unsigned long long*)(ws + kOffSup);
  unsigned long long* sorted = (unsigned long long*)(ws + kOffSorted);
  unsigned long long* keys = (unsigned long long*)(ws + kOffKeys);
  float4* boxes = (float4*)(ws + kOffBoxes);
  unsigned long long* rows = (unsigned long long*)(ws + kOffRows);
  float* out = (float*)d_out;

  // per-call re-init (harness does not re-poison between replays)
  hipMemsetAsync(ws + kOffCounter, 0, 8, stream);  // counter + sel

  hist_kernel<<<kNParts, 512, 0, stream>>>(x1, x2, x3, x4, part);
  select_kernel<<<1, kNBins, 0, stream>>>(part, sel);
  int blocks4 = (kNTot / 4 + 255) / 256;  // 3060
  compact_kernel<<<blocks4, 256, 0, stream>>>(x1, x2, x3, x4, sel, counter, keys);
  rank_kernel<<<kCap / 256, 256, kCap * sizeof(unsigned long long), stream>>>(
      keys, counter, sorted);
  decode_kernel<<<kNPad / 256, 256, 0, stream>>>(
      sorted, counter, x1, x2, x3, x4, a1, a2, a3, a4, boxes, supinit);
  iou_kernel<<<(kTopK * 64 * 64) / 256, 256, 0, stream>>>(boxes, rows);
  greedy_kernel<<<1, 64, 0, stream>>>(boxes, supinit, rows, out);
}

// Round 5
// 184.862 us; speedup vs baseline: 2.6998x; 1.3680x over previous
//
#include <hip/hip_runtime.h>

// ---------------------------------------------------------------------------
// PyramidNSMLayer: 4-level anchor decode + top-4000 selection + greedy NMS.
//
// Pipeline (all on `stream`, graph-capturable, deterministic):
//   1. memset counter/sel/rank (ws)
//   2. hist_kernel:    per-block LDS 8192-bin histogram -> partials
//   3. reduce_kernel:  column-sum 128 partials -> hist (parallel, coalesced)
//   4. select_kernel:  smallest bin B with suffix-count >= 4000
//   5. compact_kernel: gather (score,index) keys for bin >= B  (~4.4K items)
//   6. rank_kernel:    rank-by-counting exact sort (keys distinct), 2D-split
//                      (i-tile x j-chunk), partial counts via atomicAdd
//   7. scatter_kernel: sorted[rank[i]] = key[i]
//   8. decode_kernel:  decode top-4000 ranks into boxes + supinit bitmask
//   9. iou_kernel:     upper-triangle 4000 x 4096 bitmask of IoU > 0.5
//  10. greedy_kernel:  1-wave SEQUENTIAL-SCAN greedy, rows streamed HBM->LDS
//                      with counted vmcnt prefetch; emits 300 rois.
// ---------------------------------------------------------------------------

namespace {

constexpr int kNTot = 3133440;   // total anchors across levels
constexpr int kB1 = 2359296;     // 512*512*9
constexpr int kB2 = 2949120;     // + 256*256*9
constexpr int kB3 = 3096576;     // + 128*128*9
constexpr int kNBins = 8192;
constexpr int kNParts = 128;     // histogram partial blocks
constexpr int kCap = 8192;       // candidate buffer capacity
constexpr int kTopK = 4000;
constexpr int kNPad = 4096;      // padded candidate count for 64-bit words
constexpr int kNRois = 300;
constexpr int kChunk = 32;       // greedy scan chunk (rows per stage)
constexpr int kNChunks = kTopK / kChunk;  // 125
constexpr int kJChunk = 2048;    // rank j-chunk (16KB LDS)
constexpr int kITile = 256;      // rank i-tile (threads per block)

// ws byte offsets (16-aligned where vector-read)
constexpr size_t kOffPart    = 0;         // 128 * 8192 * u32 = 4 MiB
constexpr size_t kOffHist    = 4194304;   // 8192 * u32 = 32768
constexpr size_t kOffCounter = 4227072;   // u32
constexpr size_t kOffSel     = 4227076;   // u32
constexpr size_t kOffRank    = 4227080;   // 8192 * u32 = 32768
constexpr size_t kOffSup     = 4259848;   // 64 * u64 = 512
constexpr size_t kOffSorted  = 4260368;   // 4096 * u64 = 32768  (16-aligned)
constexpr size_t kOffKeys    = 4293136;   // 8192 * u64 = 65536  (16-aligned)
constexpr size_t kOffBoxes   = 4358672;   // pad to 16 -> 4358672? (see below)
// 4293136 + 65536 = 4358672 (16-aligned). boxes 4096*16 = 65536.
constexpr size_t kOffRows    = 4424208;   // pad: 4358672+65536=4424208 (16-al)
// rows: 4000 * 64 * u64 = 2048000 -> end = 6,472,208 bytes total ws usage.

// NOTE: layout (h,w,9,6) is fully linear in anchor index a: score = x[6a],
// deltas = x[6a+2..5]; anchors (h,w,9,4): anchor a at anc[4a].

struct LevelPick { const float* x; unsigned local; };

__device__ __forceinline__ LevelPick pick_level(unsigned g, const float* x1, const float* x2,
                                                const float* x3, const float* x4) {
  LevelPick p;
  if (g < (unsigned)kB1)      { p.x = x1; p.local = g; }
  else if (g < (unsigned)kB2) { p.x = x2; p.local = g - kB1; }
  else if (g < (unsigned)kB3) { p.x = x3; p.local = g - kB2; }
  else                        { p.x = x4; p.local = g - kB3; }
  return p;
}

__device__ __forceinline__ int score_bin(float s) {
  int b = (int)(s * (float)kNBins);
  return min(max(b, 0), kNBins - 1);
}

// Load 4 consecutive anchors' scores with aligned float4s (anchor group g0%4==0):
// floats f[0..23] hold scores at offsets {0,6,12,18}.
__device__ __forceinline__ void load_scores4(const float* x, unsigned local0, float s[4]) {
  const float4* p = (const float4*)(x + (size_t)local0 * 6);
  float4 q0 = p[0], q1 = p[1], q3 = p[3], q4 = p[4];
  s[0] = q0.x; s[1] = q1.z; s[2] = q3.x; s[3] = q4.z;
}

// 128 blocks x 1024: per-block LDS 8192-bin histogram, plain-store partials.
__global__ void hist_kernel(const float* __restrict__ x1, const float* __restrict__ x2,
                            const float* __restrict__ x3, const float* __restrict__ x4,
                            unsigned* __restrict__ part) {
  __shared__ unsigned h[kNBins];
  for (int i = threadIdx.x; i < kNBins; i += 1024) h[i] = 0;
  __syncthreads();
  for (int t = blockIdx.x * 1024 + threadIdx.x; t < kNTot / 4; t += kNParts * 1024) {
    unsigned g0 = (unsigned)t * 4;
    LevelPick lp = pick_level(g0, x1, x2, x3, x4);
    float s[4];
    load_scores4(lp.x, lp.local, s);
    #pragma unroll
    for (int i = 0; i < 4; ++i) atomicAdd(&h[score_bin(s[i])], 1u);
  }
  __syncthreads();
  for (int i = threadIdx.x; i < kNBins; i += 1024)
    part[blockIdx.x * kNBins + i] = h[i];
}

// 32 blocks x 256: hist[b] = sum over partials (coalesced columns).
__global__ void reduce_kernel(const unsigned* __restrict__ part, unsigned* __restrict__ hist) {
  int b = blockIdx.x * 256 + threadIdx.x;
  unsigned t = 0;
  for (int p = 0; p < kNParts; ++p) t += part[p * kNBins + b];
  hist[b] = t;
}

// 1 block, 1024 threads: find smallest bin B with suffix-count >= kTopK.
__global__ void select_kernel(const unsigned* __restrict__ hist, unsigned* __restrict__ sel) {
  __shared__ unsigned csum[1024];
  unsigned t = 0;
  int c0 = threadIdx.x * 8;
  for (int b = c0; b < c0 + 8; ++b) t += hist[b];
  csum[threadIdx.x] = t;
  __syncthreads();
  if (threadIdx.x == 0) {
    unsigned acc = 0;
    int B = 0;
    int c;
    for (c = 1023; c >= 0; --c) {
      if (acc + csum[c] >= (unsigned)kTopK) break;
      acc += csum[c];
    }
    if (c >= 0) {
      int b;
      for (b = c * 8 + 7; b >= c * 8; --b) {
        acc += hist[b];
        if (acc >= (unsigned)kTopK) break;
      }
      B = max(b, 0);
    }
    sel[0] = (unsigned)B;
  }
}

__global__ void compact_kernel(const float* __restrict__ x1, const float* __restrict__ x2,
                               const float* __restrict__ x3, const float* __restrict__ x4,
                               const unsigned* __restrict__ sel,
                               unsigned* __restrict__ counter,
                               unsigned long long* __restrict__ keys) {
  int t = blockIdx.x * blockDim.x + threadIdx.x;
  if (t >= kNTot / 4) return;
  unsigned g0 = (unsigned)t * 4;
  LevelPick lp = pick_level(g0, x1, x2, x3, x4);
  float s[4];
  load_scores4(lp.x, lp.local, s);
  unsigned B = sel[0];
  #pragma unroll
  for (int i = 0; i < 4; ++i) {
    if ((unsigned)score_bin(s[i]) >= B) {
      unsigned pos = atomicAdd(counter, 1u);
      if (pos < (unsigned)kCap) {
        unsigned g = g0 + i;
        // key: high 32 = score bits (scores >= 0 so monotonic), low 32 = ~index
        // -> rank by key DESC gives (score desc, index asc) == lax.top_k order.
        keys[pos] = ((unsigned long long)__float_as_uint(s[i]) << 32) |
                    (unsigned long long)(0xFFFFFFFFu - g);
      }
    }
  }
}

// Exact sort by rank-counting: keys distinct -> rank_i = #{j: key_j > key_i}
// is a bijection onto 0..n-1, independent of the (nondeterministic) atomic
// compaction order. 2D grid: bid = itile * (kCap/kJChunk) + jchunk. Each block
// stages its j-chunk (16KB) in LDS; each thread owns one i and accumulates a
// partial count with 4 independent LDS read streams (ILP), then one atomicAdd.
__global__ void rank_kernel(const unsigned long long* __restrict__ keys,
                            const unsigned* __restrict__ counter,
                            unsigned* __restrict__ rankArr) {
  __shared__ unsigned long long lk[kJChunk];
  int n = min((int)*counter, kCap);
  int itile = blockIdx.x / (kCap / kJChunk);
  int jc = blockIdx.x % (kCap / kJChunk);
  int i0 = itile * kITile;
  int j0 = jc * kJChunk;
  if (i0 >= n || j0 >= n) return;
  for (int j = threadIdx.x; j < kJChunk; j += kITile) {
    int jj = j0 + j;
    lk[j] = (jj < n) ? keys[jj] : 0ull;  // zero-pad: 0 never counts as greater
  }
  __syncthreads();
  int i = i0 + threadIdx.x;
  unsigned long long ki = (i < n) ? keys[i] : ~0ull;
  int r0 = 0, r1 = 0, r2 = 0, r3 = 0;
  const ulonglong2* p2 = (const ulonglong2*)lk;  // 1024 entries
  #pragma unroll 4
  for (int j = 0; j < kJChunk / 8; ++j) {        // 256 iters, 4 streams
    ulonglong2 a = p2[j];
    ulonglong2 b = p2[256 + j];
    ulonglong2 c = p2[512 + j];
    ulonglong2 d = p2[768 + j];
    r0 += (int)(a.x > ki) + (int)(a.y > ki);
    r1 += (int)(b.x > ki) + (int)(b.y > ki);
    r2 += (int)(c.x > ki) + (int)(c.y > ki);
    r3 += (int)(d.x > ki) + (int)(d.y > ki);
  }
  if (i < n) atomicAdd(&rankArr[i], (unsigned)(r0 + r1 + r2 + r3));
}

// 32 blocks x 256: sorted[rank[i]] = keys[i].
__global__ void scatter_kernel(const unsigned long long* __restrict__ keys,
                               const unsigned* __restrict__ counter,
                               const unsigned* __restrict__ rankArr,
                               unsigned long long* __restrict__ sorted) {
  int i = blockIdx.x * 256 + threadIdx.x;
  int n = min((int)*counter, kCap);
  if (i < n) {
    unsigned r = rankArr[i];
    if (r < (unsigned)kNPad) sorted[r] = keys[i];
  }
}

__device__ __forceinline__ void decode_box(unsigned g,
                                           const float* __restrict__ x1, const float* __restrict__ x2,
                                           const float* __restrict__ x3, const float* __restrict__ x4,
                                           const float* __restrict__ a1, const float* __restrict__ a2,
                                           const float* __restrict__ a3, const float* __restrict__ a4,
                                           float4* box) {
  const float* x;
  const float* anc;
  unsigned local;
  if (g < (unsigned)kB1)      { x = x1; anc = a1; local = g; }
  else if (g < (unsigned)kB2) { x = x2; anc = a2; local = g - kB1; }
  else if (g < (unsigned)kB3) { x = x3; anc = a3; local = g - kB2; }
  else                        { x = x4; anc = a4; local = g - kB3; }
  const float* xe = x + (size_t)local * 6;
  float dy = xe[2], dx = xe[3], dh = xe[4], dwv = xe[5];
  const float* ae = anc + (size_t)local * 4;
  float ay1 = ae[0], ax1 = ae[1], ay2 = ae[2], ax2 = ae[3];
  float ah = ay2 - ay1;
  float aw = ax2 - ax1;
  float acy = ay1 + 0.5f * ah;
  float acx = ax1 + 0.5f * aw;
  float cy = acy + dy * ah;
  float cx = acx + dx * aw;
  float bh = ah * expf(dh);
  float bw = aw * expf(dwv);
  box->x = fminf(fmaxf(cy - 0.5f * bh, 0.0f), 2048.0f);
  box->y = fminf(fmaxf(cx - 0.5f * bw, 0.0f), 2048.0f);
  box->z = fminf(fmaxf(cy + 0.5f * bh, 0.0f), 2048.0f);
  box->w = fminf(fmaxf(cx + 0.5f * bw, 0.0f), 2048.0f);
}

// 16 blocks x 256: decode rank r's box (zero beyond top-k / count), emit
// supinit words (bit set == inert: score < 0.5 or padding).
__global__ void decode_kernel(const unsigned long long* __restrict__ sorted,
                              const unsigned* __restrict__ counter,
                              const float* __restrict__ x1, const float* __restrict__ x2,
                              const float* __restrict__ x3, const float* __restrict__ x4,
                              const float* __restrict__ a1, const float* __restrict__ a2,
                              const float* __restrict__ a3, const float* __restrict__ a4,
                              float4* __restrict__ boxes,
                              unsigned long long* __restrict__ supinit) {
  int r = blockIdx.x * 256 + threadIdx.x;
  int n = min((int)*counter, kTopK);
  unsigned long long key = (r < n) ? sorted[r] : 0ull;
  float4 box = make_float4(0.f, 0.f, 0.f, 0.f);
  float sc = 0.f;
  if (key != 0ull) {
    sc = __uint_as_float((unsigned)(key >> 32));
    unsigned g = 0xFFFFFFFFu - (unsigned)(key & 0xFFFFFFFFull);
    if (g < (unsigned)kNTot) decode_box(g, x1, x2, x3, x4, a1, a2, a3, a4, &box);
  }
  boxes[r] = box;
  unsigned long long dead = __ballot(!(sc >= 0.5f));
  if ((threadIdx.x & 63) == 0) supinit[r >> 6] = dead;
}

// One wave per 64-column word: rows[i][w] bit j = (IoU(box_i, box_{64w+j}) > 0.5).
// Upper triangle only (wc >= row/64): greedy never consumes bits for columns
// below the current scan position, so lower words may hold stale junk.
__global__ void iou_kernel(const float4* __restrict__ boxes,
                           unsigned long long* __restrict__ rows) {
  int wave = (blockIdx.x * blockDim.x + threadIdx.x) >> 6;
  int lane = threadIdx.x & 63;
  if (wave >= kTopK * 64) return;
  int row = wave >> 6;
  int wc = wave & 63;
  if (wc < (row >> 6)) return;  // lower-triangle word: never consumed
  int j = wc * 64 + lane;
  float4 bi = boxes[row];
  float4 bj = boxes[j];
  float yy1 = fmaxf(bi.x, bj.x);
  float xx1 = fmaxf(bi.y, bj.y);
  float yy2 = fminf(bi.z, bj.z);
  float xx2 = fminf(bi.w, bj.w);
  float inter = fmaxf(yy2 - yy1, 0.0f) * fmaxf(xx2 - xx1, 0.0f);
  float ar1 = (bi.z - bi.x) * (bi.w - bi.y);
  float ar2 = (bj.z - bj.x) * (bj.w - bj.y);
  float iou = inter / (ar1 + ar2 - inter + 1e-9f);
  unsigned long long m = __ballot(iou > 0.5f);
  if (lane == 0) rows[(size_t)row * 64 + wc] = m;
}

__device__ __forceinline__ void glds16(const void* g, void* l) {
  __builtin_amdgcn_global_load_lds(
      (const __attribute__((address_space(1))) unsigned int*)g,
      (__attribute__((address_space(3))) unsigned int*)l, 16, 0, 0);
}

// Stage one chunk (32 rows x 512B = 16KB) of the rows table into LDS.
// 16 x global_load_lds dwordx4: instr i covers bytes [i*1024, i*1024+1024).
__device__ __forceinline__ void stage_chunk(const unsigned long long* rows, int chunk,
                                            unsigned long long* dst, int lane) {
  const char* src = (const char*)(rows + (size_t)chunk * kChunk * 64);
  char* d = (char*)dst;
  #pragma unroll
  for (int i = 0; i < 16; ++i) {
    glds16(src + i * 1024 + lane * 16, d + i * 1024);
  }
}

// 1 wave. Greedy argmax over a score-desc-sorted list == forward sequential
// scan: visit ranks 0..3999 in order; an unsuppressed rank IS the next pick.
// Row addresses are therefore sequential -> double-buffered LDS staging with
// counted vmcnt fully hides HBM latency. Lane l holds sup word l (64 ranks).
__global__ void greedy_kernel(const float4* __restrict__ boxes,
                              const unsigned long long* __restrict__ supinit,
                              const unsigned long long* __restrict__ rows,
                              float* __restrict__ out) {
  __shared__ unsigned long long rowbuf[2][kChunk * 64];  // 2 x 16KB
  __shared__ int picksLds[kNRois];
  const int lane = threadIdx.x;
  unsigned long long sup = supinit[lane];
  stage_chunk(rows, 0, &rowbuf[0][0], lane);
  stage_chunk(rows, 1, &rowbuf[1][0], lane);
  int count = 0;
  int curw = -1;
  unsigned long long curword = 0;
  for (int c = 0; c < kNChunks; ++c) {
    if (c + 1 < kNChunks) {
      asm volatile("s_waitcnt vmcnt(16)" ::: "memory");   // chunk c arrived
    } else {
      asm volatile("s_waitcnt vmcnt(0)" ::: "memory");
    }
    __builtin_amdgcn_sched_barrier(0);
    const int b = c & 1;
    unsigned long long rowcur = rowbuf[b][lane];  // slot 0 (1-deep ds pipeline)
    const int base = c * kChunk;
    for (int i = 0; i < kChunk; ++i) {
      unsigned long long rownext = (i + 1 < kChunk) ? rowbuf[b][(i + 1) * 64 + lane] : 0ull;
      const int r = base + i;
      const int w = r >> 6;
      if (w != curw) { curw = w; curword = __shfl(sup, w); }
      if (((curword >> (r & 63)) & 1ull) == 0ull) {
        // pick rank r
        if (lane == 0) picksLds[count] = r;
        ++count;
        sup |= rowcur;
        curword |= __shfl(rowcur, w) | (1ull << (r & 63));
        if (lane == w) sup |= (1ull << (r & 63));  // self (deg. zero-area boxes)
        if (count == kNRois) break;
      }
      rowcur = rownext;
    }
    if (count == kNRois) break;
    if (c + 2 < kNChunks) stage_chunk(rows, c + 2, &rowbuf[b][0], lane);
    if (__ballot(~sup != 0ull) == 0ull) break;  // nothing alive anywhere ahead
  }
  __syncthreads();
  for (int p = lane; p < kNRois; p += 64) {
    float4 bx = make_float4(0.f, 0.f, 0.f, 0.f);
    if (p < count) bx = boxes[picksLds[p]];
    ((float4*)out)[p] = bx;  // zero-pads the tail; replaces out memset
  }
}

}  // namespace

extern "C" void kernel_launch(void* const* d_in, const int* in_sizes, int n_in,
                              void* d_out, int out_size, void* d_ws, size_t ws_size,
                              hipStream_t stream) {
  const float* x1 = (const float*)d_in[0];
  const float* a1 = (const float*)d_in[1];
  const float* x2 = (const float*)d_in[2];
  const float* a2 = (const float*)d_in[3];
  const float* x3 = (const float*)d_in[4];
  const float* a3 = (const float*)d_in[5];
  const float* x4 = (const float*)d_in[6];
  const float* a4 = (const float*)d_in[7];

  char* ws = (char*)d_ws;
  unsigned* part = (unsigned*)(ws + kOffPart);
  unsigned* hist = (unsigned*)(ws + kOffHist);
  unsigned* counter = (unsigned*)(ws + kOffCounter);
  unsigned* sel = (unsigned*)(ws + kOffSel);
  unsigned* rankArr = (unsigned*)(ws + kOffRank);
  unsigned long long* supinit = (unsigned long long*)(ws + kOffSup);
  unsigned long long* sorted = (unsigned long long*)(ws + kOffSorted);
  unsigned long long* keys = (unsigned long long*)(ws + kOffKeys);
  float4* boxes = (float4*)(ws + kOffBoxes);
  unsigned long long* rows = (unsigned long long*)(ws + kOffRows);
  float* out = (float*)d_out;

  // per-call re-init: counter + sel + rankArr (contiguous region)
  hipMemsetAsync(ws + kOffCounter, 0, 8 + kCap * sizeof(unsigned), stream);

  hist_kernel<<<kNParts, 1024, 0, stream>>>(x1, x2, x3, x4, part);
  reduce_kernel<<<kNBins / 256, 256, 0, stream>>>(part, hist);
  select_kernel<<<1, 1024, 0, stream>>>(hist, sel);
  int blocks4 = (kNTot / 4 + 255) / 256;  // 3060
  compact_kernel<<<blocks4, 256, 0, stream>>>(x1, x2, x3, x4, sel, counter, keys);
  rank_kernel<<<(kCap / kITile) * (kCap / kJChunk), kITile, 0, stream>>>(
      keys, counter, rankArr);
  scatter_kernel<<<kCap / 256, 256, 0, stream>>>(keys, counter, rankArr, sorted);
  decode_kernel<<<kNPad / 256, 256, 0, stream>>>(
      sorted, counter, x1, x2, x3, x4, a1, a2, a3, a4, boxes, supinit);
  iou_kernel<<<(kTopK * 64 * 64) / 256, 256, 0, stream>>>(boxes, rows);
  greedy_kernel<<<1, 64, 0, stream>>>(boxes, supinit, rows, out);
}

// Round 6
// 172.661 us; speedup vs baseline: 2.8906x; 1.0707x over previous
//
#include <hip/hip_runtime.h>

// ---------------------------------------------------------------------------
// PyramidNSMLayer: 4-level anchor decode + top-4000 selection + greedy NMS.
//
// Pipeline (all on `stream`, graph-capturable, deterministic):
//   1. memset counter/sel/rank (ws)
//   2. hist_kernel:    per-block LDS 8192-bin histogram -> partials
//   3. reduce_kernel:  column-sum 128 partials -> hist (parallel, coalesced)
//   4. select_kernel:  smallest bin B with suffix-count >= 4000
//   5. compact_kernel: gather (score,index) keys for bin >= B  (~4.4K items)
//   6. rank_kernel:    rank-by-counting exact sort (keys distinct), 2D-split
//   7. scatter_kernel: sorted[rank[i]] = key[i]
//   8. decode_kernel:  decode top-4000 ranks into boxes + supinit bitmask
//   9. iou_kernel:     upper-triangle 4000 x 4096 bitmask of IoU > 0.5
//  10. greedy_kernel:  8 waves / 1 CU: waves 1-7 stream the rows table into
//                      an 8-slot LDS ring (2-deep per-wave pipelines, counted
//                      vmcnt), wave 0 does the serial greedy with SKIP-SCAN
//                      (ctz over alive mask -> suppressed ranks cost zero).
// ---------------------------------------------------------------------------

namespace {

constexpr int kNTot = 3133440;   // total anchors across levels
constexpr int kB1 = 2359296;     // 512*512*9
constexpr int kB2 = 2949120;     // + 256*256*9
constexpr int kB3 = 3096576;     // + 128*128*9
constexpr int kNBins = 8192;
constexpr int kNParts = 128;     // histogram partial blocks
constexpr int kCap = 8192;       // candidate buffer capacity
constexpr int kTopK = 4000;
constexpr int kNPad = 4096;      // padded candidate count for 64-bit words
constexpr int kNRois = 300;
constexpr int kChunk = 32;       // greedy scan chunk (rows per slot)
constexpr int kNChunks = kTopK / kChunk;  // 125
constexpr int kNSlots = 8;       // LDS ring slots (16KB each)
constexpr int kNPref = 7;        // prefetcher waves
constexpr int kJChunk = 2048;    // rank j-chunk (16KB LDS)
constexpr int kITile = 256;      // rank i-tile (threads per block)

// ws byte offsets (16-aligned where vector-read)
constexpr size_t kOffPart    = 0;         // 128 * 8192 * u32 = 4 MiB
constexpr size_t kOffHist    = 4194304;   // 8192 * u32 = 32768
constexpr size_t kOffCounter = 4227072;   // u32
constexpr size_t kOffSel     = 4227076;   // u32
constexpr size_t kOffRank    = 4227080;   // 8192 * u32 = 32768
constexpr size_t kOffSup     = 4259848;   // 64 * u64 = 512
constexpr size_t kOffSorted  = 4260368;   // 4096 * u64 = 32768
constexpr size_t kOffKeys    = 4293136;   // 8192 * u64 = 65536
constexpr size_t kOffBoxes   = 4358672;   // 4096 * float4 = 65536
constexpr size_t kOffRows    = 4424208;   // 4000 * 64 * u64 = 2048000
// total ws usage: 6,472,208 bytes

// NOTE: layout (h,w,9,6) is fully linear in anchor index a: score = x[6a],
// deltas = x[6a+2..5]; anchors (h,w,9,4): anchor a at anc[4a].

struct LevelPick { const float* x; unsigned local; };

__device__ __forceinline__ LevelPick pick_level(unsigned g, const float* x1, const float* x2,
                                                const float* x3, const float* x4) {
  LevelPick p;
  if (g < (unsigned)kB1)      { p.x = x1; p.local = g; }
  else if (g < (unsigned)kB2) { p.x = x2; p.local = g - kB1; }
  else if (g < (unsigned)kB3) { p.x = x3; p.local = g - kB2; }
  else                        { p.x = x4; p.local = g - kB3; }
  return p;
}

__device__ __forceinline__ int score_bin(float s) {
  int b = (int)(s * (float)kNBins);
  return min(max(b, 0), kNBins - 1);
}

// Load 4 consecutive anchors' scores with aligned float4s (anchor group g0%4==0):
// floats f[0..23] hold scores at offsets {0,6,12,18}.
__device__ __forceinline__ void load_scores4(const float* x, unsigned local0, float s[4]) {
  const float4* p = (const float4*)(x + (size_t)local0 * 6);
  float4 q0 = p[0], q1 = p[1], q3 = p[3], q4 = p[4];
  s[0] = q0.x; s[1] = q1.z; s[2] = q3.x; s[3] = q4.z;
}

// 128 blocks x 1024: per-block LDS 8192-bin histogram, plain-store partials.
__global__ void hist_kernel(const float* __restrict__ x1, const float* __restrict__ x2,
                            const float* __restrict__ x3, const float* __restrict__ x4,
                            unsigned* __restrict__ part) {
  __shared__ unsigned h[kNBins];
  for (int i = threadIdx.x; i < kNBins; i += 1024) h[i] = 0;
  __syncthreads();
  for (int t = blockIdx.x * 1024 + threadIdx.x; t < kNTot / 4; t += kNParts * 1024) {
    unsigned g0 = (unsigned)t * 4;
    LevelPick lp = pick_level(g0, x1, x2, x3, x4);
    float s[4];
    load_scores4(lp.x, lp.local, s);
    #pragma unroll
    for (int i = 0; i < 4; ++i) atomicAdd(&h[score_bin(s[i])], 1u);
  }
  __syncthreads();
  for (int i = threadIdx.x; i < kNBins; i += 1024)
    part[blockIdx.x * kNBins + i] = h[i];
}

// 32 blocks x 256: hist[b] = sum over partials (coalesced columns).
__global__ void reduce_kernel(const unsigned* __restrict__ part, unsigned* __restrict__ hist) {
  int b = blockIdx.x * 256 + threadIdx.x;
  unsigned t = 0;
  for (int p = 0; p < kNParts; ++p) t += part[p * kNBins + b];
  hist[b] = t;
}

// 1 block, 1024 threads: find smallest bin B with suffix-count >= kTopK.
__global__ void select_kernel(const unsigned* __restrict__ hist, unsigned* __restrict__ sel) {
  __shared__ unsigned csum[1024];
  unsigned t = 0;
  int c0 = threadIdx.x * 8;
  for (int b = c0; b < c0 + 8; ++b) t += hist[b];
  csum[threadIdx.x] = t;
  __syncthreads();
  if (threadIdx.x == 0) {
    unsigned acc = 0;
    int B = 0;
    int c;
    for (c = 1023; c >= 0; --c) {
      if (acc + csum[c] >= (unsigned)kTopK) break;
      acc += csum[c];
    }
    if (c >= 0) {
      int b;
      for (b = c * 8 + 7; b >= c * 8; --b) {
        acc += hist[b];
        if (acc >= (unsigned)kTopK) break;
      }
      B = max(b, 0);
    }
    sel[0] = (unsigned)B;
  }
}

__global__ void compact_kernel(const float* __restrict__ x1, const float* __restrict__ x2,
                               const float* __restrict__ x3, const float* __restrict__ x4,
                               const unsigned* __restrict__ sel,
                               unsigned* __restrict__ counter,
                               unsigned long long* __restrict__ keys) {
  int t = blockIdx.x * blockDim.x + threadIdx.x;
  if (t >= kNTot / 4) return;
  unsigned g0 = (unsigned)t * 4;
  LevelPick lp = pick_level(g0, x1, x2, x3, x4);
  float s[4];
  load_scores4(lp.x, lp.local, s);
  unsigned B = sel[0];
  #pragma unroll
  for (int i = 0; i < 4; ++i) {
    if ((unsigned)score_bin(s[i]) >= B) {
      unsigned pos = atomicAdd(counter, 1u);
      if (pos < (unsigned)kCap) {
        unsigned g = g0 + i;
        // key: high 32 = score bits (scores >= 0 so monotonic), low 32 = ~index
        // -> rank by key DESC gives (score desc, index asc) == lax.top_k order.
        keys[pos] = ((unsigned long long)__float_as_uint(s[i]) << 32) |
                    (unsigned long long)(0xFFFFFFFFu - g);
      }
    }
  }
}

// Exact sort by rank-counting: keys distinct -> rank_i = #{j: key_j > key_i}
// is a bijection onto 0..n-1, independent of the (nondeterministic) atomic
// compaction order. 2D grid: bid = itile * (kCap/kJChunk) + jchunk. Each block
// stages its j-chunk (16KB) in LDS; each thread owns one i and accumulates a
// partial count with 4 independent LDS read streams (ILP), then one atomicAdd.
__global__ void rank_kernel(const unsigned long long* __restrict__ keys,
                            const unsigned* __restrict__ counter,
                            unsigned* __restrict__ rankArr) {
  __shared__ unsigned long long lk[kJChunk];
  int n = min((int)*counter, kCap);
  int itile = blockIdx.x / (kCap / kJChunk);
  int jc = blockIdx.x % (kCap / kJChunk);
  int i0 = itile * kITile;
  int j0 = jc * kJChunk;
  if (i0 >= n || j0 >= n) return;
  for (int j = threadIdx.x; j < kJChunk; j += kITile) {
    int jj = j0 + j;
    lk[j] = (jj < n) ? keys[jj] : 0ull;  // zero-pad: 0 never counts as greater
  }
  __syncthreads();
  int i = i0 + threadIdx.x;
  unsigned long long ki = (i < n) ? keys[i] : ~0ull;
  int r0 = 0, r1 = 0, r2 = 0, r3 = 0;
  const ulonglong2* p2 = (const ulonglong2*)lk;  // 1024 entries
  #pragma unroll 4
  for (int j = 0; j < kJChunk / 8; ++j) {        // 256 iters, 4 streams
    ulonglong2 a = p2[j];
    ulonglong2 b = p2[256 + j];
    ulonglong2 c = p2[512 + j];
    ulonglong2 d = p2[768 + j];
    r0 += (int)(a.x > ki) + (int)(a.y > ki);
    r1 += (int)(b.x > ki) + (int)(b.y > ki);
    r2 += (int)(c.x > ki) + (int)(c.y > ki);
    r3 += (int)(d.x > ki) + (int)(d.y > ki);
  }
  if (i < n) atomicAdd(&rankArr[i], (unsigned)(r0 + r1 + r2 + r3));
}

// 32 blocks x 256: sorted[rank[i]] = keys[i].
__global__ void scatter_kernel(const unsigned long long* __restrict__ keys,
                               const unsigned* __restrict__ counter,
                               const unsigned* __restrict__ rankArr,
                               unsigned long long* __restrict__ sorted) {
  int i = blockIdx.x * 256 + threadIdx.x;
  int n = min((int)*counter, kCap);
  if (i < n) {
    unsigned r = rankArr[i];
    if (r < (unsigned)kNPad) sorted[r] = keys[i];
  }
}

__device__ __forceinline__ void decode_box(unsigned g,
                                           const float* __restrict__ x1, const float* __restrict__ x2,
                                           const float* __restrict__ x3, const float* __restrict__ x4,
                                           const float* __restrict__ a1, const float* __restrict__ a2,
                                           const float* __restrict__ a3, const float* __restrict__ a4,
                                           float4* box) {
  const float* x;
  const float* anc;
  unsigned local;
  if (g < (unsigned)kB1)      { x = x1; anc = a1; local = g; }
  else if (g < (unsigned)kB2) { x = x2; anc = a2; local = g - kB1; }
  else if (g < (unsigned)kB3) { x = x3; anc = a3; local = g - kB2; }
  else                        { x = x4; anc = a4; local = g - kB3; }
  const float* xe = x + (size_t)local * 6;
  float dy = xe[2], dx = xe[3], dh = xe[4], dwv = xe[5];
  const float* ae = anc + (size_t)local * 4;
  float ay1 = ae[0], ax1 = ae[1], ay2 = ae[2], ax2 = ae[3];
  float ah = ay2 - ay1;
  float aw = ax2 - ax1;
  float acy = ay1 + 0.5f * ah;
  float acx = ax1 + 0.5f * aw;
  float cy = acy + dy * ah;
  float cx = acx + dx * aw;
  float bh = ah * expf(dh);
  float bw = aw * expf(dwv);
  box->x = fminf(fmaxf(cy - 0.5f * bh, 0.0f), 2048.0f);
  box->y = fminf(fmaxf(cx - 0.5f * bw, 0.0f), 2048.0f);
  box->z = fminf(fmaxf(cy + 0.5f * bh, 0.0f), 2048.0f);
  box->w = fminf(fmaxf(cx + 0.5f * bw, 0.0f), 2048.0f);
}

// 16 blocks x 256: decode rank r's box (zero beyond top-k / count), emit
// supinit words (bit set == inert: score < 0.5 or padding).
__global__ void decode_kernel(const unsigned long long* __restrict__ sorted,
                              const unsigned* __restrict__ counter,
                              const float* __restrict__ x1, const float* __restrict__ x2,
                              const float* __restrict__ x3, const float* __restrict__ x4,
                              const float* __restrict__ a1, const float* __restrict__ a2,
                              const float* __restrict__ a3, const float* __restrict__ a4,
                              float4* __restrict__ boxes,
                              unsigned long long* __restrict__ supinit) {
  int r = blockIdx.x * 256 + threadIdx.x;
  int n = min((int)*counter, kTopK);
  unsigned long long key = (r < n) ? sorted[r] : 0ull;
  float4 box = make_float4(0.f, 0.f, 0.f, 0.f);
  float sc = 0.f;
  if (key != 0ull) {
    sc = __uint_as_float((unsigned)(key >> 32));
    unsigned g = 0xFFFFFFFFu - (unsigned)(key & 0xFFFFFFFFull);
    if (g < (unsigned)kNTot) decode_box(g, x1, x2, x3, x4, a1, a2, a3, a4, &box);
  }
  boxes[r] = box;
  unsigned long long dead = __ballot(!(sc >= 0.5f));
  if ((threadIdx.x & 63) == 0) supinit[r >> 6] = dead;
}

// One wave per 64-column word: rows[i][w] bit j = (IoU(box_i, box_{64w+j}) > 0.5).
// Upper triangle only (wc >= row/64): greedy never consumes bits for columns
// below the current scan position, so lower words may hold stale junk.
__global__ void iou_kernel(const float4* __restrict__ boxes,
                           unsigned long long* __restrict__ rows) {
  int wave = (blockIdx.x * blockDim.x + threadIdx.x) >> 6;
  int lane = threadIdx.x & 63;
  if (wave >= kTopK * 64) return;
  int row = wave >> 6;
  int wc = wave & 63;
  if (wc < (row >> 6)) return;  // lower-triangle word: never consumed
  int j = wc * 64 + lane;
  float4 bi = boxes[row];
  float4 bj = boxes[j];
  float yy1 = fmaxf(bi.x, bj.x);
  float xx1 = fmaxf(bi.y, bj.y);
  float yy2 = fminf(bi.z, bj.z);
  float xx2 = fminf(bi.w, bj.w);
  float inter = fmaxf(yy2 - yy1, 0.0f) * fmaxf(xx2 - xx1, 0.0f);
  float ar1 = (bi.z - bi.x) * (bi.w - bi.y);
  float ar2 = (bj.z - bj.x) * (bj.w - bj.y);
  float iou = inter / (ar1 + ar2 - inter + 1e-9f);
  unsigned long long m = __ballot(iou > 0.5f);
  if (lane == 0) rows[(size_t)row * 64 + wc] = m;
}

__device__ __forceinline__ void glds16(const void* g, void* l) {
  __builtin_amdgcn_global_load_lds(
      (const __attribute__((address_space(1))) unsigned int*)g,
      (__attribute__((address_space(3))) unsigned int*)l, 16, 0, 0);
}

// Stage one chunk (32 rows x 512B = 16KB) of the rows table into LDS.
// 16 x global_load_lds dwordx4: instr i covers bytes [i*1024, i*1024+1024).
__device__ __forceinline__ void stage_chunk(const unsigned long long* rows, int chunk,
                                            unsigned long long* dst, int lane) {
  const char* src = (const char*)(rows + (size_t)chunk * kChunk * 64);
  char* d = (char*)dst;
  #pragma unroll
  for (int i = 0; i < 16; ++i) {
    glds16(src + i * 1024 + lane * 16, d + i * 1024);
  }
}

// 8 waves, 1 CU. Wave 0 = scan; waves 1..7 = prefetchers streaming the rows
// table into an 8-slot LDS ring (each wave pipelines 2 chunks: counted
// vmcnt(16)). Flag protocol: ready[c] set after vmcnt(0|16) drains chunk c's
// loads; scan bumps consumed AFTER it is done with chunk c (and only after
// having waited on ready[c], so two prefetchers never write one slot
// concurrently); prefetcher for chunk c waits consumed >= c-7 (slot free).
// Scan uses SKIP-SCAN: alive mask per 32-rank window, ctz jumps to picks.
__global__ __launch_bounds__(512, 1) void greedy_kernel(
    const float4* __restrict__ boxes,
    const unsigned long long* __restrict__ supinit,
    const unsigned long long* __restrict__ rows,
    float* __restrict__ out) {
  __shared__ unsigned long long slots[kNSlots][kChunk * 64];  // 8 x 16KB
  __shared__ unsigned readyF[kNChunks];
  __shared__ unsigned consumedF;
  __shared__ unsigned doneF;
  __shared__ int picksLds[kNRois];
  __shared__ int countSh;

  volatile unsigned* vready = readyF;
  volatile unsigned* vconsumed = &consumedF;
  volatile unsigned* vdone = &doneF;

  const int tid = threadIdx.x;
  const int wid = tid >> 6;
  const int lane = tid & 63;

  for (int i = tid; i < kNChunks; i += 512) readyF[i] = 0;
  if (tid == 0) { consumedF = 0; doneF = 0; countSh = 0; }
  __syncthreads();

  if (wid > 0) {
    // ---- prefetcher wave: chunks c == wid-1 (mod 7), 2-deep pipeline ----
    int c = wid - 1;
    bool primed = false;
    if (c < kNChunks) {
      while (!*vdone && (int)*vconsumed < c - (kNSlots - 1))
        __builtin_amdgcn_s_sleep(1);
      if (!*vdone) {
        stage_chunk(rows, c, &slots[c & (kNSlots - 1)][0], lane);
        primed = true;
      }
    }
    while (primed) {
      int nxt = c + kNPref;
      bool staged_next = false;
      if (nxt < kNChunks) {
        while (!*vdone && (int)*vconsumed < nxt - (kNSlots - 1))
          __builtin_amdgcn_s_sleep(1);
        if (!*vdone) {
          stage_chunk(rows, nxt, &slots[nxt & (kNSlots - 1)][0], lane);
          staged_next = true;
        }
      }
      if (staged_next) {
        asm volatile("s_waitcnt vmcnt(16)" ::: "memory");  // chunk c landed
      } else {
        asm volatile("s_waitcnt vmcnt(0)" ::: "memory");
      }
      if (lane == 0) vready[c] = 1;
      if (!staged_next) break;
      c = nxt;
    }
  } else {
    // ---- scan wave ----
    unsigned long long sup = supinit[lane];
    int count = 0;
    for (int c = 0; c < kNChunks; ++c) {
      while (*vready == 0 ? (vready[c] == 0) : (vready[c] == 0))
        __builtin_amdgcn_s_sleep(1);
      asm volatile("" ::: "memory");  // data reads stay below the spin
      const unsigned long long* buf = &slots[c & (kNSlots - 1)][0];
      const int base = c * kChunk;
      const int w = base >> 6;
      const int sh = base & 63;  // 0 or 32
      unsigned long long cw = __shfl(sup, w);
      unsigned mask = (unsigned)((~cw) >> sh);  // alive bits in this window
      while (mask != 0u && count < kNRois) {
        const int i = __builtin_ctz(mask);
        const int r = base + i;
        unsigned long long row = buf[i * 64 + lane];
        if (lane == 0) picksLds[count] = r;
        ++count;
        sup |= row;
        if (lane == w) sup |= 1ull << (r & 63);  // self (deg. zero-area boxes)
        unsigned long long rww = __shfl(row, w);
        mask &= ~(unsigned)(rww >> sh);
        mask &= ~(1u << i);
      }
      if (lane == 0) *vconsumed = (unsigned)(c + 1);
      if (count == kNRois) break;
      if (__ballot(~sup != 0ull) == 0ull) break;  // nothing alive ahead
    }
    if (lane == 0) { countSh = count; *vdone = 1u; }
  }
  __syncthreads();
  const int cnt = countSh;
  for (int p = tid; p < kNRois; p += 512) {
    float4 bx = make_float4(0.f, 0.f, 0.f, 0.f);
    if (p < cnt) bx = boxes[picksLds[p]];
    ((float4*)out)[p] = bx;  // zero-pads the tail
  }
}

}  // namespace

extern "C" void kernel_launch(void* const* d_in, const int* in_sizes, int n_in,
                              void* d_out, int out_size, void* d_ws, size_t ws_size,
                              hipStream_t stream) {
  const float* x1 = (const float*)d_in[0];
  const float* a1 = (const float*)d_in[1];
  const float* x2 = (const float*)d_in[2];
  const float* a2 = (const float*)d_in[3];
  const float* x3 = (const float*)d_in[4];
  const float* a3 = (const float*)d_in[5];
  const float* x4 = (const float*)d_in[6];
  const float* a4 = (const float*)d_in[7];

  char* ws = (char*)d_ws;
  unsigned* part = (unsigned*)(ws + kOffPart);
  unsigned* hist = (unsigned*)(ws + kOffHist);
  unsigned* counter = (unsigned*)(ws + kOffCounter);
  unsigned* sel = (unsigned*)(ws + kOffSel);
  unsigned* rankArr = (unsigned*)(ws + kOffRank);
  unsigned long long* supinit = (unsigned long long*)(ws + kOffSup);
  unsigned long long* sorted = (unsigned long long*)(ws + kOffSorted);
  unsigned long long* keys = (unsigned long long*)(ws + kOffKeys);
  float4* boxes = (float4*)(ws + kOffBoxes);
  unsigned long long* rows = (unsigned long long*)(ws + kOffRows);
  float* out = (float*)d_out;

  // per-call re-init: counter + sel + rankArr (contiguous region)
  hipMemsetAsync(ws + kOffCounter, 0, 8 + kCap * sizeof(unsigned), stream);

  hist_kernel<<<kNParts, 1024, 0, stream>>>(x1, x2, x3, x4, part);
  reduce_kernel<<<kNBins / 256, 256, 0, stream>>>(part, hist);
  select_kernel<<<1, 1024, 0, stream>>>(hist, sel);
  int blocks4 = (kNTot / 4 + 255) / 256;  // 3060
  compact_kernel<<<blocks4, 256, 0, stream>>>(x1, x2, x3, x4, sel, counter, keys);
  rank_kernel<<<(kCap / kITile) * (kCap / kJChunk), kITile, 0, stream>>>(
      keys, counter, rankArr);
  scatter_kernel<<<kCap / 256, 256, 0, stream>>>(keys, counter, rankArr, sorted);
  decode_kernel<<<kNPad / 256, 256, 0, stream>>>(
      sorted, counter, x1, x2, x3, x4, a1, a2, a3, a4, boxes, supinit);
  iou_kernel<<<(kTopK * 64 * 64) / 256, 256, 0, stream>>>(boxes, rows);
  greedy_kernel<<<1, 512, 0, stream>>>(boxes, supinit, rows, out);
}